// Round 12
// baseline (674.629 us; speedup 1.0000x reference)
//
#include <hip/hip_runtime.h>
#include <math.h>

#define IN_DIM 20
#define DIM 128
#define HH 8
#define LL 3
#define BB 2
#define NP 192
#define DHH 16
#define C2 256
#define NN (NP*NP)
#define EPS 1e-5f

// padded conv-input geometry
#define PR 200
#define PC 224

typedef __bf16 bf16x8 __attribute__((ext_vector_type(8)));
typedef float  f32x16 __attribute__((ext_vector_type(16)));

union Pack8 { __bf16 h[8]; uint4 u; };

#define GLOAD16(gp, lp) \
  __builtin_amdgcn_global_load_lds((const __attribute__((address_space(1))) uint4*)(gp), \
                                   (__attribute__((address_space(3))) uint4*)(lp), 16, 0, 0)

// ---------------- init: conv1d over seq for both x and c (+ t-major CcT) ----------------
__global__ void k_conv_init(const float* __restrict__ seq, const float* __restrict__ w1,
                            const float* __restrict__ w2, float* __restrict__ X,
                            float* __restrict__ Cc, float* __restrict__ CcT) {
  int t = blockIdx.x, b = blockIdx.y, oc = threadIdx.x;
  __shared__ float ss[3][IN_DIM];
  if (threadIdx.x < 3*IN_DIM) {
    int k = threadIdx.x / IN_DIM, ic = threadIdx.x % IN_DIM;
    int tt = t + k - 1;
    ss[k][ic] = (tt >= 0 && tt < NP) ? seq[(b*NP + tt)*IN_DIM + ic] : 0.f;
  }
  __syncthreads();
  float a1 = 0.f, a2 = 0.f;
  #pragma unroll
  for (int ic = 0; ic < IN_DIM; ic++) {
    #pragma unroll
    for (int k = 0; k < 3; k++) {
      float sv = ss[k][ic];
      a1 = fmaf(w1[(oc*IN_DIM + ic)*3 + k], sv, a1);
      a2 = fmaf(w2[(oc*IN_DIM + ic)*3 + k], sv, a2);
    }
  }
  X[(b*NP + t)*DIM + oc] = a1;
  Cc[(b*DIM + oc)*NP + t] = a2;
  CcT[(size_t)(b*NP + t)*DIM + oc] = a2;
}

// ---------------- conv1d + BN + relu: WIDE (768 thr); writes c-major AND t-major ----------------
__global__ __launch_bounds__(768)
void k_conv1d_bn_relu(const float* __restrict__ cin, const float* __restrict__ w,
                      const float* __restrict__ g, const float* __restrict__ bb,
                      float* __restrict__ cout, float* __restrict__ coutT) {
  int oc = blockIdx.x;
  int tid = threadIdx.x;
  int t = tid % NP;
  int sub = tid / NP;            // 0..3
  int b = sub & 1, ih = sub >> 1;
  float acc = 0.f;
  for (int ic = ih*64; ic < ih*64 + 64; ic++) {
    const float* cr = cin + (b*DIM + ic)*NP;
    const float* wr = w + (oc*DIM + ic)*3;
    float lf = (t > 0)      ? cr[t-1] : 0.f;
    float mf = cr[t];
    float rf = (t < NP-1)   ? cr[t+1] : 0.f;
    acc = fmaf(lf, wr[0], acc);
    acc = fmaf(mf, wr[1], acc);
    acc = fmaf(rf, wr[2], acc);
  }
  __shared__ float sp[4][NP];
  __shared__ float sb[768];
  sp[sub][t] = acc;
  __syncthreads();
  float raw = sp[b][t] + sp[2 + b][t];
  sb[tid] = (sub < 2) ? raw : raw * raw;
  __syncthreads();
  for (int s = 192; s >= 3; s >>= 1) {
    if (tid < s) sb[tid] += sb[tid + s];
    int u = tid - 384;
    if (u >= 0 && u < s) sb[tid] += sb[tid + s];
    __syncthreads();
  }
  float mean = (sb[0] + sb[1] + sb[2]) / 384.f;
  float var  = (sb[384] + sb[385] + sb[386]) / 384.f - mean*mean;
  float rstd = rsqrtf(var + EPS);
  if (sub < 2) {
    float v = fmaxf((raw - mean)*rstd*g[oc] + bb[oc], 0.f);
    cout[(b*DIM + oc)*NP + t] = v;
    coutT[(size_t)(b*NP + t)*DIM + oc] = v;
  }
}

// ---------------- small-weight transpose: wT[e][j] = w[j][e], 13 matrices ----------------
__global__ void k_wtrans(const float* __restrict__ wq, const float* __restrict__ wk,
                         const float* __restrict__ wv, const float* __restrict__ wl,
                         const float* __restrict__ fcw,
                         float* __restrict__ wqt, float* __restrict__ wkt,
                         float* __restrict__ wvt, float* __restrict__ wlt,
                         float* __restrict__ fct) {
  int m = blockIdx.y;
  const float* src; float* dst;
  if (m < 3)       { src = wq + (size_t)m*DIM*DIM;     dst = wqt + (size_t)m*DIM*DIM; }
  else if (m < 6)  { src = wk + (size_t)(m-3)*DIM*DIM; dst = wkt + (size_t)(m-3)*DIM*DIM; }
  else if (m < 9)  { src = wv + (size_t)(m-6)*DIM*DIM; dst = wvt + (size_t)(m-6)*DIM*DIM; }
  else if (m < 12) { src = wl + (size_t)(m-9)*DIM*DIM; dst = wlt + (size_t)(m-9)*DIM*DIM; }
  else             { src = fcw;                        dst = fct; }
  int tile = blockIdx.x;
  int ti = tile >> 2, tj = tile & 3;
  int r = threadIdx.x >> 3, c4 = threadIdx.x & 7;
  __shared__ float t[32][33];
  float4 v = *(const float4*)(src + (ti*32 + r)*DIM + tj*32 + c4*4);
  t[r][c4*4+0] = v.x; t[r][c4*4+1] = v.y; t[r][c4*4+2] = v.z; t[r][c4*4+3] = v.w;
  __syncthreads();
  float4 o;
  o.x = t[c4*4+0][r]; o.y = t[c4*4+1][r]; o.z = t[c4*4+2][r]; o.w = t[c4*4+3][r];
  *(float4*)(dst + (tj*32 + r)*DIM + ti*32 + c4*4) = o;
}

// ---------------- layer-0: x = LN(x + ccT), q,k,v — WIDE (384 thr) ----------------
__global__ __launch_bounds__(384)
void k_lnqkv(float* __restrict__ X, const float* __restrict__ ccT,
             const float* __restrict__ g, const float* __restrict__ bb,
             const float* __restrict__ wqt, const float* __restrict__ bq,
             const float* __restrict__ wkt, const float* __restrict__ bk,
             const float* __restrict__ wvt, const float* __restrict__ bv,
             float* __restrict__ Q, float* __restrict__ K, float* __restrict__ V) {
  int t = blockIdx.x, b = blockIdx.y;
  int tid = threadIdx.x;
  int lane = tid & 63, wave = tid >> 6;
  __shared__ float sy[DIM];
  __shared__ float sred[2];
  size_t o = (size_t)(b*NP + t)*DIM;
  float v = 0.f;
  if (tid < DIM) v = X[o + tid] + ccT[o + tid];
  if (tid < DIM) {
    float s = v;
    #pragma unroll
    for (int m = 32; m > 0; m >>= 1) s += __shfl_xor(s, m);
    if (lane == 0) sred[wave] = s;
  }
  __syncthreads();
  float mean = (sred[0] + sred[1]) * (1.f/128.f);
  float dv = v - mean;
  __syncthreads();
  if (tid < DIM) {
    float q = dv*dv;
    #pragma unroll
    for (int m = 32; m > 0; m >>= 1) q += __shfl_xor(q, m);
    if (lane == 0) sred[wave] = q;
  }
  __syncthreads();
  float var = (sred[0] + sred[1]) * (1.f/128.f);
  float rstd = rsqrtf(var + EPS);
  if (tid < DIM) {
    float xn = dv * rstd * g[tid] + bb[tid];
    X[o + tid] = xn;
    sy[tid] = xn;
  }
  __syncthreads();
  {
    int d2 = tid & 127, m = tid >> 7;
    const float* wt_m = (m == 0) ? wqt : (m == 1) ? wkt : wvt;
    const float* b_m  = (m == 0) ? bq  : (m == 1) ? bk  : bv;
    float* out_m      = (m == 0) ? Q   : (m == 1) ? K   : V;
    float acc = b_m[d2];
    for (int ee = 0; ee < DIM; ee++) acc = fmaf(wt_m[ee*DIM + d2], sy[ee], acc);
    int h = d2 >> 4, dh = d2 & 15;
    out_m[((size_t)(b*HH + h)*NP + t)*DHH + dh] = fmaxf(acc, 0.f);
  }
}

// ---------------- conv2d weight prep (coalesced reads via LDS) ----------------
__global__ void k_wprep(const float* __restrict__ w, __bf16* __restrict__ wtb) {
  int l = blockIdx.x / C2, oc = blockIdx.x % C2;
  int tid = threadIdx.x;
  __shared__ float swt[C2*9];
  const float4* wsrc = (const float4*)(w + ((size_t)(l*C2 + oc))*C2*9);
  for (int idx = tid; idx < 576; idx += 256) ((float4*)swt)[idx] = wsrc[idx];
  __syncthreads();
  for (int v = tid; v < 288; v += 256) {
    int chunk = v / 18, rem = v % 18;
    int kk = rem >> 1, kh = rem & 1;
    Pack8 p;
    #pragma unroll
    for (int e = 0; e < 8; e++)
      p.h[e] = (__bf16)swt[(chunk*16 + kh*8 + e)*9 + kk];
    size_t unit = ((((size_t)(l*16 + chunk)*9 + kk)*2 + kh)*256 + oc);
    ((uint4*)wtb)[unit] = p.u;
  }
}

// ---------------- layer-0 conv input build from t-major sources; zeroes 3x STAT2 ----------------
__global__ void k_make_convin(const float* __restrict__ CcT, const float* __restrict__ CLT0,
                              __bf16* __restrict__ inb, float* __restrict__ STATALL) {
  int idx = blockIdx.x*256 + threadIdx.x;
  if (blockIdx.x == 0) {
    for (int z = threadIdx.x; z < 3*2*C2; z += 256) STATALL[z] = 0.f;
  }
  int kh = idx & 1;
  int t = idx >> 1;
  int gcol = t % PC; int t2 = t / PC;
  int grow = t2 % PR; int t3 = t2 / PR;
  int chunk = t3 & 15; int b = t3 >> 4;
  int i = grow - 1, j = gcol - 8;
  Pack8 p;
  if ((unsigned)i < 192u && (unsigned)j < 192u) {
    int cbase = chunk*16 + kh*8;
    const float* pa;
    const float* pb;
    if (cbase < DIM) {
      pa = CcT  + (size_t)(b*NP + i)*DIM + cbase;
      pb = CLT0 + (size_t)(b*NP + i)*DIM + cbase;
    } else {
      pa = CcT  + (size_t)(b*NP + j)*DIM + (cbase - DIM);
      pb = CLT0 + (size_t)(b*NP + j)*DIM + (cbase - DIM);
    }
    #pragma unroll
    for (int e = 0; e < 8; e++) p.h[e] = (__bf16)(pa[e] + pb[e]);
  } else {
    #pragma unroll
    for (int e = 0; e < 8; e++) p.h[e] = (__bf16)0.f;
  }
  ((uint4*)inb)[idx] = p.u;
}

// ---------------- heavy kernel: implicit-GEMM bf16 MFMA 3x3 conv, 64-oc wave tile ----------------
// grid (3 jt, 48 it, 8 = b*4+oct), block 128 (2 waves).
// Block tile: 64 oc x (4 rows x 64 cols); wave tile 64 oc x 2 rows x 64 cols.
// Per chunk per wave: 42 ds_read_b128 for 72 MFMAs (0.58 r/MFMA) -> MFMA-bound.
// Staging: W 1152 u + I 960 u (6 rows x 80 x 2kh) = 33.8 KB/buffer; dbuf 67.6 KB -> 2 blocks/CU.
__global__ __launch_bounds__(128, 1)
void k_conv2d_mfma(const __bf16* __restrict__ inb,   // padded [b][16][PR][PC][2][8]
                   const __bf16* __restrict__ wtb,   // [16][9][2][256][8] (layer slice)
                   __bf16* __restrict__ rawb,        // [b][32][192][192][8]
                   float* __restrict__ STAT2) {
  __shared__ __align__(16) uint4 sbuf[2*2112];       // 67584 B
  int tid = threadIdx.x;
  int jt = blockIdx.x, it = blockIdx.y, zz = blockIdx.z;
  int b = zz >> 2, oct = zz & 3;
  int i0 = it*4, j0 = jt*64, oc0 = oct*64;
  int lane = tid & 63, wv = tid >> 6;                // wv 0..1
  int ln31 = lane & 31, khl = lane >> 5;

  const uint4* gW = (const uint4*)wtb;
  const uint4* gI = (const uint4*)inb;

  f32x16 acc[2][2][2];   // [rr][om][ch]
  #pragma unroll
  for (int r = 0; r < 2; r++)
    #pragma unroll
    for (int m = 0; m < 2; m++)
      #pragma unroll
      for (int n = 0; n < 2; n++)
        #pragma unroll
        for (int q = 0; q < 16; q++) acc[r][m][n][q] = 0.f;

  // staging: 33 wave-segments of 64 lanes; this wave's slots L = t*2 + wv.
  // L 0..17 = W (1152 units); L 18..32 = I (960 units).
  const uint4* gp[17];
  int lofs[17];
  int gstride[17];
  bool gvalid[17];
  #pragma unroll
  for (int t = 0; t < 17; t++) {
    int L = t*2 + wv;
    gvalid[t] = (L < 33);
    if (L < 18) {                              // W segment
      int u = L*64 + lane;                     // 0..1151
      int kkh = u >> 6;                        // 0..17
      int ocl = u & 63;
      gp[t] = gW + (size_t)kkh*256 + oc0 + ocl;
      lofs[t] = u;
      gstride[t] = 4608;
    } else {                                   // I segment
      int u = (L - 18)*64 + lane;              // 0..959
      int r = u / 160;
      int rem = u % 160;
      int kh = rem / 80;
      int c = rem % 80;
      gp[t] = gI + (((size_t)(b*16)*PR) + i0 + r)*PC*2 + (size_t)(j0 + c)*2 + kh;
      lofs[t] = 1152 + u;
      gstride[t] = PR*PC*2;
    }
  }

  auto issue = [&](int buf) {
    uint4* lbase = sbuf + buf*2112;
    #pragma unroll
    for (int t = 0; t < 17; t++) {
      if (gvalid[t]) {
        GLOAD16(gp[t], lbase + lofs[t]);
        gp[t] += gstride[t];
      }
    }
  };

  issue(0);

  for (int chunk = 0; chunk < 16; ++chunk) {
    int buf = chunk & 1;
    __syncthreads();                   // staged data visible; prev buf's ds_reads done
    if (chunk < 15) issue(buf ^ 1);
    const __bf16* Wl = (const __bf16*)(sbuf + buf*2112);
    const __bf16* Il = (const __bf16*)(sbuf + buf*2112 + 1152);
    #pragma unroll
    for (int kj = 0; kj < 3; kj++) {
      // B fragments for staged rows wv*2 + rx (rx=0..3), both col-halves
      bf16x8 bfr[4][2];
      #pragma unroll
      for (int rx = 0; rx < 4; rx++) {
        int r = wv*2 + rx;
        #pragma unroll
        for (int ch = 0; ch < 2; ch++) {
          int c = ch*32 + ln31 + kj + 7;
          bfr[rx][ch] = *(const bf16x8*)(Il + ((r*2 + khl)*80 + c)*8);
        }
      }
      #pragma unroll
      for (int ki = 0; ki < 3; ki++) {
        int kk = ki*3 + kj;
        bf16x8 a0 = *(const bf16x8*)(Wl + ((kk*2 + khl)*64 +      ln31)*8);
        bf16x8 a1 = *(const bf16x8*)(Wl + ((kk*2 + khl)*64 + 32 + ln31)*8);
        #pragma unroll
        for (int rr = 0; rr < 2; rr++) {
          #pragma unroll
          for (int ch = 0; ch < 2; ch++) {
            acc[rr][0][ch] = __builtin_amdgcn_mfma_f32_32x32x16_bf16(a0, bfr[rr + ki][ch], acc[rr][0][ch], 0, 0, 0);
            acc[rr][1][ch] = __builtin_amdgcn_mfma_f32_32x32x16_bf16(a1, bfr[rr + ki][ch], acc[rr][1][ch], 0, 0, 0);
          }
        }
      }
    }
  }

  __syncthreads();                     // all ds_reads done; overlay LDS for epilogue
  float* trAll = (float*)sbuf;
  float* tr = trAll + wv*(32*33);
  float* sstat = trAll + 2*32*33;      // 128 floats: [64 sum][64 sumsq]
  if (tid < 128) sstat[tid] = 0.f;
  __syncthreads();

  // fused BN2 partial stats
  #pragma unroll
  for (int om = 0; om < 2; om++) {
    #pragma unroll
    for (int reg = 0; reg < 16; reg++) {
      float v00 = acc[0][om][0][reg], v01 = acc[0][om][1][reg];
      float v10 = acc[1][om][0][reg], v11 = acc[1][om][1][reg];
      float s = v00 + v01 + v10 + v11;
      float s2 = v00*v00 + v01*v01 + v10*v10 + v11*v11;
      #pragma unroll
      for (int msk = 1; msk <= 16; msk <<= 1) { s += __shfl_xor(s, msk); s2 += __shfl_xor(s2, msk); }
      if (ln31 == 0) {
        int oc_l = om*32 + (reg & 3) + 8*(reg >> 2) + 4*khl;
        atomicAdd(&sstat[oc_l], s);
        atomicAdd(&sstat[64 + oc_l], s2);
      }
    }
  }

  // packed bf16 output via wave-local LDS transpose
  uint4* RAWu = (uint4*)rawb;
  #pragma unroll
  for (int rr = 0; rr < 2; rr++) {
    int i = i0 + wv*2 + rr;
    #pragma unroll
    for (int om = 0; om < 2; om++) {
      int Gb = (oc0 + om*32) >> 3;
      #pragma unroll
      for (int ch = 0; ch < 2; ch++) {
        #pragma unroll
        for (int reg = 0; reg < 16; reg++) {
          int r = (reg & 3) + 8*(reg >> 2) + 4*khl;
          tr[r*33 + ln31] = acc[rr][om][ch][reg];
        }
        __builtin_amdgcn_s_waitcnt(0);
        #pragma unroll
        for (int gs = 0; gs < 2; gs++) {
          int g = khl + gs*2;
          Pack8 p;
          #pragma unroll
          for (int e = 0; e < 8; e++) p.h[e] = (__bf16)tr[(g*8 + e)*33 + ln31];
          RAWu[((size_t)(b*32 + Gb + g)*192 + i)*192 + j0 + ch*32 + ln31] = p.u;
        }
        __builtin_amdgcn_s_waitcnt(0);
      }
    }
  }

  __syncthreads();
  if (tid < 64) {
    atomicAdd(&STAT2[oc0 + tid], sstat[tid]);
    atomicAdd(&STAT2[C2 + oc0 + tid], sstat[64 + tid]);
  }
}

// ---------------- fused: BN2 norm+relu, gate proj, next conv input: WIDER (768 thr) ----------------
template<int WRITE_NEXT>
__global__ __launch_bounds__(768)
void k_bn2_norm_gate(const __bf16* __restrict__ rawb, const float* __restrict__ STAT2,
                     const float* __restrict__ g, const float* __restrict__ bb,
                     const float* __restrict__ wd, const float* __restrict__ CLnT,
                     __bf16* __restrict__ inb_next, float* __restrict__ tg) {
  int i = blockIdx.x, b = blockIdx.y;
  int tid = threadIdx.x;
  int j = tid % 192, qt = tid / 192;       // quarter 0..3
  __shared__ float sscale[C2], sshift[C2], swd[HH*C2];
  __shared__ float sg[4][HH][192];
  const float inv = 1.f / (float)(BB*NN);
  for (int c = tid; c < C2; c += 768) {
    float mean = STAT2[c] * inv;
    float var  = STAT2[C2 + c] * inv - mean*mean;
    float rstd = rsqrtf(var + EPS);
    float sc = rstd * g[c];
    sscale[c] = sc;
    sshift[c] = bb[c] - mean*sc;
  }
  for (int idx = tid; idx < HH*C2; idx += 768) swd[idx] = wd[idx];
  __syncthreads();
  float gacc[HH] = {};
  const uint4* RAWu = (const uint4*)rawb;
  const float* clrow_i = CLnT ? CLnT + (size_t)(b*NP + i)*DIM : nullptr;
  const float* clrow_j = CLnT ? CLnT + (size_t)(b*NP + j)*DIM : nullptr;
  for (int cu = qt*8; cu < qt*8 + 8; cu++) {
    Pack8 pr; pr.u = RAWu[((size_t)(b*32 + cu)*NP + i)*NP + j];
    Pack8 p;
    int cbase = cu*8;
    const float* clp = (WRITE_NEXT && cbase < DIM) ? clrow_i + cbase
                     : (WRITE_NEXT ? clrow_j + (cbase - DIM) : nullptr);
    #pragma unroll
    for (int e = 0; e < 8; e++) {
      int c = cbase + e;
      float v = (float)pr.h[e];
      v = fmaxf(fmaf(v, sscale[c], sshift[c]), 0.f);
      if (WRITE_NEXT) p.h[e] = (__bf16)(v + clp[e]);
      #pragma unroll
      for (int h = 0; h < HH; h++) gacc[h] = fmaf(v, swd[h*C2 + c], gacc[h]);
    }
    if (WRITE_NEXT) {
      size_t unit = ((((size_t)(b*16 + (cu>>1))*PR + (i+1))*PC + (j+8))*2 + (cu&1));
      ((uint4*)inb_next)[unit] = p.u;
    }
  }
  #pragma unroll
  for (int h = 0; h < HH; h++) sg[qt][h][j] = gacc[h];
  __syncthreads();
  if (qt == 0) {
    #pragma unroll
    for (int h = 0; h < HH; h++)
      tg[((size_t)(b*HH + h)*NP + i)*NP + j] = sg[0][h][j] + sg[1][h][j] + sg[2][h][j] + sg[3][h][j];
  }
}

// ---------------- gate = sigmoid(t + t^T + bias), coalesced tiled transpose ----------------
__global__ void k_gate(const float* __restrict__ tg, const float* __restrict__ wdb,
                       float* __restrict__ gate) {
  int tile = blockIdx.x;
  int hb = blockIdx.y;
  int b = hb >> 3, h = hb & 7;
  size_t bh = (size_t)(b*HH + h);
  int ti = tile / 6, tj = tile % 6;
  int r = threadIdx.x >> 3, c4 = threadIdx.x & 7;
  __shared__ float tB[32][33];
  const float* base = tg + bh*NN;
  float4 vb = *(const float4*)(base + (tj*32 + r)*NP + ti*32 + c4*4);
  tB[r][c4*4+0] = vb.x; tB[r][c4*4+1] = vb.y; tB[r][c4*4+2] = vb.z; tB[r][c4*4+3] = vb.w;
  __syncthreads();
  float4 va = *(const float4*)(base + (ti*32 + r)*NP + tj*32 + c4*4);
  float bias = wdb[h];
  float4 o;
  o.x = 1.f / (1.f + expf(-(va.x + tB[c4*4+0][r] + bias)));
  o.y = 1.f / (1.f + expf(-(va.y + tB[c4*4+1][r] + bias)));
  o.z = 1.f / (1.f + expf(-(va.z + tB[c4*4+2][r] + bias)));
  o.w = 1.f / (1.f + expf(-(va.w + tB[c4*4+3][r] + bias)));
  *(float4*)(gate + bh*NN + (ti*32 + r)*NP + tj*32 + c4*4) = o;
}

// ---------------- MEGA-fused attnx: WIDE (384 thr), t-major ccn ----------------
template<int MODE>
__global__ __launch_bounds__(384)
void k_attnx(const float* __restrict__ Q, const float* __restrict__ K,
             const float* __restrict__ V, const float* __restrict__ gate,
             const float* __restrict__ mask,
             float* __restrict__ X,
             const float* __restrict__ wlt, const float* __restrict__ bl,
             const float* __restrict__ ccnT,
             const float* __restrict__ lng, const float* __restrict__ lnb,
             const float* __restrict__ wqt, const float* __restrict__ bq,
             const float* __restrict__ wkt, const float* __restrict__ bk,
             const float* __restrict__ wvt, const float* __restrict__ bv,
             float* __restrict__ Qn, float* __restrict__ Kn, float* __restrict__ Vn,
             const float* __restrict__ fct, const float* __restrict__ fb,
             float* __restrict__ out) {
  int i = blockIdx.x, b = blockIdx.y;
  int tid = threadIdx.x;
  int j = tid % 192, half = tid / 192;
  int lane = tid & 63, wave = tid >> 6;
  __shared__ float sq[DIM];
  __shared__ float sattn[HH][NP];
  __shared__ float spv[3][DIM];
  __shared__ float supd[DIM];
  __shared__ float sy[DIM];
  __shared__ float sxp[3][DIM];
  __shared__ float sredm[HH][3];
  __shared__ float sreds[HH][3];
  __shared__ float sred[2];
  float mk = mask[b*NP + j];

  if (tid < DIM) {
    int h = tid >> 4, d = tid & 15;
    sq[tid] = Q[(((size_t)(b*HH + h))*NP + i)*DHH + d];
  }
  __syncthreads();

  float a[4], gt[4];
  #pragma unroll
  for (int hh = 0; hh < 4; hh++) {
    int h = half*4 + hh;
    size_t bh = (size_t)(b*HH + h);
    const float4* kr = (const float4*)(K + (bh*NP + j)*DHH);
    const float4* qr = (const float4*)(sq + h*DHH);
    float acc = 0.f;
    #pragma unroll
    for (int q4 = 0; q4 < 4; q4++) {
      float4 qv = qr[q4], kv = kr[q4];
      acc = fmaf(qv.x, kv.x, acc); acc = fmaf(qv.y, kv.y, acc);
      acc = fmaf(qv.z, kv.z, acc); acc = fmaf(qv.w, kv.w, acc);
    }
    a[hh] = acc * 0.25f;
    gt[hh] = gate[(bh*NP + i)*NP + j];
  }
  #pragma unroll
  for (int hh = 0; hh < 4; hh++) {
    int h = half*4 + hh;
    float m = a[hh];
    #pragma unroll
    for (int s = 32; s > 0; s >>= 1) m = fmaxf(m, __shfl_xor(m, s));
    if (lane == 0) sredm[h][wave % 3] = m;
  }
  __syncthreads();
  float e[4];
  #pragma unroll
  for (int hh = 0; hh < 4; hh++) {
    int h = half*4 + hh;
    float amax = fmaxf(fmaxf(sredm[h][0], sredm[h][1]), sredm[h][2]);
    e[hh] = expf(a[hh] - amax) * mk;
    float ss = e[hh];
    #pragma unroll
    for (int s = 32; s > 0; s >>= 1) ss += __shfl_xor(ss, s);
    if (lane == 0) sreds[h][wave % 3] = ss;
  }
  __syncthreads();
  #pragma unroll
  for (int hh = 0; hh < 4; hh++) {
    int h = half*4 + hh;
    float denom = sreds[h][0] + sreds[h][1] + sreds[h][2] + 1e-6f;
    sattn[h][j] = (e[hh] / denom) * gt[hh];
  }
  __syncthreads();

  {
    int d = tid & 15, h2 = (tid >> 4) & 7, jseg = tid >> 7;
    size_t bh = (size_t)(b*HH + h2);
    float acc = 0.f;
    for (int jj = jseg*64; jj < jseg*64 + 64; jj++)
      acc = fmaf(sattn[h2][jj], V[(bh*NP + jj)*DHH + d], acc);
    spv[jseg][h2*DHH + d] = acc;
  }
  __syncthreads();
  if (tid < DIM) supd[tid] = spv[0][tid] + spv[1][tid] + spv[2][tid];
  __syncthreads();

  size_t o = (size_t)(b*NP + i)*DIM;
  if (tid < DIM) sy[tid] = X[o + tid] + supd[tid];
  __syncthreads();
  {
    int d2 = tid & 127, ks = tid >> 7;
    int e0 = ks*43, e1 = (ks == 2) ? 128 : e0 + 43;
    float acc = (ks == 0) ? bl[d2] : 0.f;
    for (int ee = e0; ee < e1; ee++) acc = fmaf(wlt[ee*DIM + d2], sy[ee], acc);
    sxp[ks][d2] = acc;
  }
  __syncthreads();
  float xr = 0.f;
  if (tid < DIM) xr = fmaxf(sxp[0][tid] + sxp[1][tid] + sxp[2][tid], 0.f);
  __syncthreads();

  if (MODE == 0) {
    float v = 0.f;
    if (tid < DIM) v = xr + ccnT[o + tid];
    if (tid < DIM) {
      float s = v;
      #pragma unroll
      for (int m = 32; m > 0; m >>= 1) s += __shfl_xor(s, m);
      if (lane == 0) sred[wave] = s;
    }
    __syncthreads();
    float mean = (sred[0] + sred[1]) * (1.f/128.f);
    float dv = v - mean;
    __syncthreads();
    if (tid < DIM) {
      float q = dv*dv;
      #pragma unroll
      for (int m = 32; m > 0; m >>= 1) q += __shfl_xor(q, m);
      if (lane == 0) sred[wave] = q;
    }
    __syncthreads();
    float var = (sred[0] + sred[1]) * (1.f/128.f);
    float rstd = rsqrtf(var + EPS);
    if (tid < DIM) {
      float xn = dv * rstd * lng[tid] + lnb[tid];
      X[o + tid] = xn;
      sy[tid] = xn;
    }
    __syncthreads();
    {
      int d2 = tid & 127, m = tid >> 7;
      const float* wt_m = (m == 0) ? wqt : (m == 1) ? wkt : wvt;
      const float* b_m  = (m == 0) ? bq  : (m == 1) ? bk  : bv;
      float* out_m      = (m == 0) ? Qn  : (m == 1) ? Kn  : Vn;
      float acc = b_m[d2];
      for (int ee = 0; ee < DIM; ee++) acc = fmaf(wt_m[ee*DIM + d2], sy[ee], acc);
      int h = d2 >> 4, dh = d2 & 15;
      out_m[((size_t)(b*HH + h)*NP + i)*DHH + dh] = fmaxf(acc, 0.f);
    }
  } else {
    if (tid < DIM) sy[tid] = xr;
    __syncthreads();
    {
      int d2 = tid & 127, ks = tid >> 7;
      int e0 = ks*43, e1 = (ks == 2) ? 128 : e0 + 43;
      float acc = (ks == 0) ? fb[d2] : 0.f;
      for (int ee = e0; ee < e1; ee++) acc = fmaf(fct[ee*DIM + d2], sy[ee], acc);
      sxp[ks][d2] = acc;
    }
    __syncthreads();
    if (tid < DIM)
      out[o + tid] = fmaxf(sxp[0][tid] + sxp[1][tid] + sxp[2][tid], 0.f);
  }
}

extern "C" void kernel_launch(void* const* d_in, const int* in_sizes, int n_in,
                              void* d_out, int out_size, void* d_ws, size_t ws_size,
                              hipStream_t stream) {
  const float* seq     = (const float*)d_in[0];
  const float* mask    = (const float*)d_in[1];
  const float* conv1_w = (const float*)d_in[2];
  const float* conv2_w = (const float*)d_in[3];
  const float* ln_g    = (const float*)d_in[4];
  const float* ln_b    = (const float*)d_in[5];
  const float* c1d_w   = (const float*)d_in[6];
  const float* bn1_g   = (const float*)d_in[7];
  const float* bn1_b   = (const float*)d_in[8];
  const float* c2d_w   = (const float*)d_in[9];
  const float* bn2_g   = (const float*)d_in[10];
  const float* bn2_b   = (const float*)d_in[11];
  const float* wq_w    = (const float*)d_in[12];
  const float* wq_b    = (const float*)d_in[13];
  const float* wk_w    = (const float*)d_in[14];
  const float* wk_b    = (const float*)d_in[15];
  const float* wv_w    = (const float*)d_in[16];
  const float* wv_b    = (const float*)d_in[17];
  const float* wd_w    = (const float*)d_in[18];
  const float* wd_b    = (const float*)d_in[19];
  const float* wl_w    = (const float*)d_in[20];
  const float* wl_b    = (const float*)d_in[21];
  const float* fc_w    = (const float*)d_in[22];
  const float* fc_b    = (const float*)d_in[23];
  float* out = (float*)d_out;

  float* ws = (float*)d_ws;
  float* X    = ws; ws += BB*NP*DIM;
  float* Cc   = ws; ws += BB*DIM*NP;
  float* CcT  = ws; ws += BB*DIM*NP;
  float* CL0  = ws; ws += BB*DIM*NP;
  float* CL1  = ws; ws += BB*DIM*NP;
  float* CL2  = ws; ws += BB*DIM*NP;
  float* CLT0 = ws; ws += BB*DIM*NP;
  float* CLT1 = ws; ws += BB*DIM*NP;
  float* CLT2 = ws; ws += BB*DIM*NP;
  float* Q0   = ws; ws += BB*NP*DIM;
  float* K0   = ws; ws += BB*NP*DIM;
  float* V0   = ws; ws += BB*NP*DIM;
  float* Q1   = ws; ws += BB*NP*DIM;
  float* K1   = ws; ws += BB*NP*DIM;
  float* V1   = ws; ws += BB*NP*DIM;
  float* TG   = ws; ws += (size_t)BB*HH*NN;
  float* GATE = ws; ws += (size_t)BB*HH*NN;
  float* WQT  = ws; ws += (size_t)LL*DIM*DIM;
  float* WKT  = ws; ws += (size_t)LL*DIM*DIM;
  float* WVT  = ws; ws += (size_t)LL*DIM*DIM;
  float* WLT  = ws; ws += (size_t)LL*DIM*DIM;
  float* FCT  = ws; ws += (size_t)DIM*DIM;
  float* STATALL = ws; ws += 3*2*C2;
  __bf16* RAW = (__bf16*)ws; ws += (size_t)BB*C2*NN/2;
  __bf16* INB = (__bf16*)ws; ws += (size_t)BB*16*PR*PC*2*16/4;
  __bf16* WTB = (__bf16*)ws; ws += (size_t)LL*C2*C2*9/2;

  k_wtrans<<<dim3(16, 13), 256, 0, stream>>>(wq_w, wk_w, wv_w, wl_w, fc_w,
                                             WQT, WKT, WVT, WLT, FCT);
  k_wprep<<<LL*C2, 256, 0, stream>>>(c2d_w, WTB);
  k_conv_init<<<dim3(NP, BB), DIM, 0, stream>>>(seq, conv1_w, conv2_w, X, Cc, CcT);
  k_conv1d_bn_relu<<<DIM, 768, 0, stream>>>(Cc,  c1d_w + 0*(size_t)DIM*DIM*3, bn1_g + 0*DIM, bn1_b + 0*DIM, CL0, CLT0);
  k_conv1d_bn_relu<<<DIM, 768, 0, stream>>>(CL0, c1d_w + 1*(size_t)DIM*DIM*3, bn1_g + 1*DIM, bn1_b + 1*DIM, CL1, CLT1);
  k_conv1d_bn_relu<<<DIM, 768, 0, stream>>>(CL1, c1d_w + 2*(size_t)DIM*DIM*3, bn1_g + 2*DIM, bn1_b + 2*DIM, CL2, CLT2);
  k_make_convin<<<(BB*16*PR*PC*2)/256, 256, 0, stream>>>(CcT, CLT0, INB, STATALL);
  k_lnqkv<<<dim3(NP, BB), 384, 0, stream>>>(X, CLT0, ln_g, ln_b,
                                            WQT, wq_b, WKT, wk_b, WVT, wv_b, Q0, K0, V0);

  // ---- layer 0 ----
  k_conv2d_mfma<<<dim3(3, 48, 8), 128, 0, stream>>>(INB, WTB + 0*(size_t)16*9*2*256*8, RAW, STATALL + 0*2*C2);
  k_bn2_norm_gate<1><<<dim3(NP, BB), 768, 0, stream>>>(RAW, STATALL + 0*2*C2, bn2_g + 0*C2, bn2_b + 0*C2,
                                                       wd_w + 0*(size_t)HH*C2, CLT1, INB, TG);
  k_gate<<<dim3(36, 16), 256, 0, stream>>>(TG, wd_b + 0*HH, GATE);
  k_attnx<0><<<dim3(NP, BB), 384, 0, stream>>>(Q0, K0, V0, GATE, mask, X,
                                               WLT + 0*(size_t)DIM*DIM, wl_b + 0*DIM,
                                               CLT1, ln_g + 1*DIM, ln_b + 1*DIM,
                                               WQT + 1*(size_t)DIM*DIM, wq_b + 1*DIM,
                                               WKT + 1*(size_t)DIM*DIM, wk_b + 1*DIM,
                                               WVT + 1*(size_t)DIM*DIM, wv_b + 1*DIM,
                                               Q1, K1, V1, nullptr, nullptr, nullptr);
  // ---- layer 1 ----
  k_conv2d_mfma<<<dim3(3, 48, 8), 128, 0, stream>>>(INB, WTB + 1*(size_t)16*9*2*256*8, RAW, STATALL + 1*2*C2);
  k_bn2_norm_gate<1><<<dim3(NP, BB), 768, 0, stream>>>(RAW, STATALL + 1*2*C2, bn2_g + 1*C2, bn2_b + 1*C2,
                                                       wd_w + 1*(size_t)HH*C2, CLT2, INB, TG);
  k_gate<<<dim3(36, 16), 256, 0, stream>>>(TG, wd_b + 1*HH, GATE);
  k_attnx<0><<<dim3(NP, BB), 384, 0, stream>>>(Q1, K1, V1, GATE, mask, X,
                                               WLT + 1*(size_t)DIM*DIM, wl_b + 1*DIM,
                                               CLT2, ln_g + 2*DIM, ln_b + 2*DIM,
                                               WQT + 2*(size_t)DIM*DIM, wq_b + 2*DIM,
                                               WKT + 2*(size_t)DIM*DIM, wk_b + 2*DIM,
                                               WVT + 2*(size_t)DIM*DIM, wv_b + 2*DIM,
                                               Q0, K0, V0, nullptr, nullptr, nullptr);
  // ---- layer 2 ----
  k_conv2d_mfma<<<dim3(3, 48, 8), 128, 0, stream>>>(INB, WTB + 2*(size_t)16*9*2*256*8, RAW, STATALL + 2*2*C2);
  k_bn2_norm_gate<0><<<dim3(NP, BB), 768, 0, stream>>>(RAW, STATALL + 2*2*C2, bn2_g + 2*C2, bn2_b + 2*C2,
                                                       wd_w + 2*(size_t)HH*C2, nullptr, nullptr, TG);
  k_gate<<<dim3(36, 16), 256, 0, stream>>>(TG, wd_b + 2*HH, GATE);
  k_attnx<1><<<dim3(NP, BB), 384, 0, stream>>>(Q0, K0, V0, GATE, mask, X,
                                               WLT + 2*(size_t)DIM*DIM, wl_b + 2*DIM,
                                               nullptr, nullptr, nullptr,
                                               nullptr, nullptr, nullptr, nullptr, nullptr, nullptr,
                                               nullptr, nullptr, nullptr,
                                               FCT, fc_b, out);
}

// Round 13
// 615.305 us; speedup vs baseline: 1.0964x; 1.0964x over previous
//
#include <hip/hip_runtime.h>
#include <math.h>

#define IN_DIM 20
#define DIM 128
#define HH 8
#define LL 3
#define BB 2
#define NP 192
#define DHH 16
#define C2 256
#define NN (NP*NP)
#define EPS 1e-5f

// padded conv-input geometry
#define PR 200
#define PC 224

typedef __bf16 bf16x8 __attribute__((ext_vector_type(8)));
typedef float  f32x16 __attribute__((ext_vector_type(16)));

union Pack8 { __bf16 h[8]; uint4 u; };

#define GLOAD16(gp, lp) \
  __builtin_amdgcn_global_load_lds((const __attribute__((address_space(1))) uint4*)(gp), \
                                   (__attribute__((address_space(3))) uint4*)(lp), 16, 0, 0)

// ---------------- init: conv1d over seq for both x and c (+ t-major CcT) ----------------
__global__ void k_conv_init(const float* __restrict__ seq, const float* __restrict__ w1,
                            const float* __restrict__ w2, float* __restrict__ X,
                            float* __restrict__ Cc, float* __restrict__ CcT) {
  int t = blockIdx.x, b = blockIdx.y, oc = threadIdx.x;
  __shared__ float ss[3][IN_DIM];
  if (threadIdx.x < 3*IN_DIM) {
    int k = threadIdx.x / IN_DIM, ic = threadIdx.x % IN_DIM;
    int tt = t + k - 1;
    ss[k][ic] = (tt >= 0 && tt < NP) ? seq[(b*NP + tt)*IN_DIM + ic] : 0.f;
  }
  __syncthreads();
  float a1 = 0.f, a2 = 0.f;
  #pragma unroll
  for (int ic = 0; ic < IN_DIM; ic++) {
    #pragma unroll
    for (int k = 0; k < 3; k++) {
      float sv = ss[k][ic];
      a1 = fmaf(w1[(oc*IN_DIM + ic)*3 + k], sv, a1);
      a2 = fmaf(w2[(oc*IN_DIM + ic)*3 + k], sv, a2);
    }
  }
  X[(b*NP + t)*DIM + oc] = a1;
  Cc[(b*DIM + oc)*NP + t] = a2;
  CcT[(size_t)(b*NP + t)*DIM + oc] = a2;
}

// ---------------- conv1d + BN + relu: WIDE (768 thr); writes c-major AND t-major ----------------
__global__ __launch_bounds__(768)
void k_conv1d_bn_relu(const float* __restrict__ cin, const float* __restrict__ w,
                      const float* __restrict__ g, const float* __restrict__ bb,
                      float* __restrict__ cout, float* __restrict__ coutT) {
  int oc = blockIdx.x;
  int tid = threadIdx.x;
  int t = tid % NP;
  int sub = tid / NP;            // 0..3
  int b = sub & 1, ih = sub >> 1;
  float acc = 0.f;
  for (int ic = ih*64; ic < ih*64 + 64; ic++) {
    const float* cr = cin + (b*DIM + ic)*NP;
    const float* wr = w + (oc*DIM + ic)*3;
    float lf = (t > 0)      ? cr[t-1] : 0.f;
    float mf = cr[t];
    float rf = (t < NP-1)   ? cr[t+1] : 0.f;
    acc = fmaf(lf, wr[0], acc);
    acc = fmaf(mf, wr[1], acc);
    acc = fmaf(rf, wr[2], acc);
  }
  __shared__ float sp[4][NP];
  __shared__ float sb[768];
  sp[sub][t] = acc;
  __syncthreads();
  float raw = sp[b][t] + sp[2 + b][t];
  sb[tid] = (sub < 2) ? raw : raw * raw;
  __syncthreads();
  for (int s = 192; s >= 3; s >>= 1) {
    if (tid < s) sb[tid] += sb[tid + s];
    int u = tid - 384;
    if (u >= 0 && u < s) sb[tid] += sb[tid + s];
    __syncthreads();
  }
  float mean = (sb[0] + sb[1] + sb[2]) / 384.f;
  float var  = (sb[384] + sb[385] + sb[386]) / 384.f - mean*mean;
  float rstd = rsqrtf(var + EPS);
  if (sub < 2) {
    float v = fmaxf((raw - mean)*rstd*g[oc] + bb[oc], 0.f);
    cout[(b*DIM + oc)*NP + t] = v;
    coutT[(size_t)(b*NP + t)*DIM + oc] = v;
  }
}

// ---------------- small-weight transpose: wT[e][j] = w[j][e], 13 matrices ----------------
__global__ void k_wtrans(const float* __restrict__ wq, const float* __restrict__ wk,
                         const float* __restrict__ wv, const float* __restrict__ wl,
                         const float* __restrict__ fcw,
                         float* __restrict__ wqt, float* __restrict__ wkt,
                         float* __restrict__ wvt, float* __restrict__ wlt,
                         float* __restrict__ fct) {
  int m = blockIdx.y;
  const float* src; float* dst;
  if (m < 3)       { src = wq + (size_t)m*DIM*DIM;     dst = wqt + (size_t)m*DIM*DIM; }
  else if (m < 6)  { src = wk + (size_t)(m-3)*DIM*DIM; dst = wkt + (size_t)(m-3)*DIM*DIM; }
  else if (m < 9)  { src = wv + (size_t)(m-6)*DIM*DIM; dst = wvt + (size_t)(m-6)*DIM*DIM; }
  else if (m < 12) { src = wl + (size_t)(m-9)*DIM*DIM; dst = wlt + (size_t)(m-9)*DIM*DIM; }
  else             { src = fcw;                        dst = fct; }
  int tile = blockIdx.x;
  int ti = tile >> 2, tj = tile & 3;
  int r = threadIdx.x >> 3, c4 = threadIdx.x & 7;
  __shared__ float t[32][33];
  float4 v = *(const float4*)(src + (ti*32 + r)*DIM + tj*32 + c4*4);
  t[r][c4*4+0] = v.x; t[r][c4*4+1] = v.y; t[r][c4*4+2] = v.z; t[r][c4*4+3] = v.w;
  __syncthreads();
  float4 o;
  o.x = t[c4*4+0][r]; o.y = t[c4*4+1][r]; o.z = t[c4*4+2][r]; o.w = t[c4*4+3][r];
  *(float4*)(dst + (tj*32 + r)*DIM + ti*32 + c4*4) = o;
}

// ---------------- layer-0: x = LN(x + ccT), q,k,v — WIDE (384 thr) ----------------
__global__ __launch_bounds__(384)
void k_lnqkv(float* __restrict__ X, const float* __restrict__ ccT,
             const float* __restrict__ g, const float* __restrict__ bb,
             const float* __restrict__ wqt, const float* __restrict__ bq,
             const float* __restrict__ wkt, const float* __restrict__ bk,
             const float* __restrict__ wvt, const float* __restrict__ bv,
             float* __restrict__ Q, float* __restrict__ K, float* __restrict__ V) {
  int t = blockIdx.x, b = blockIdx.y;
  int tid = threadIdx.x;
  int lane = tid & 63, wave = tid >> 6;
  __shared__ float sy[DIM];
  __shared__ float sred[2];
  size_t o = (size_t)(b*NP + t)*DIM;
  float v = 0.f;
  if (tid < DIM) v = X[o + tid] + ccT[o + tid];
  if (tid < DIM) {
    float s = v;
    #pragma unroll
    for (int m = 32; m > 0; m >>= 1) s += __shfl_xor(s, m);
    if (lane == 0) sred[wave] = s;
  }
  __syncthreads();
  float mean = (sred[0] + sred[1]) * (1.f/128.f);
  float dv = v - mean;
  __syncthreads();
  if (tid < DIM) {
    float q = dv*dv;
    #pragma unroll
    for (int m = 32; m > 0; m >>= 1) q += __shfl_xor(q, m);
    if (lane == 0) sred[wave] = q;
  }
  __syncthreads();
  float var = (sred[0] + sred[1]) * (1.f/128.f);
  float rstd = rsqrtf(var + EPS);
  if (tid < DIM) {
    float xn = dv * rstd * g[tid] + bb[tid];
    X[o + tid] = xn;
    sy[tid] = xn;
  }
  __syncthreads();
  {
    int d2 = tid & 127, m = tid >> 7;
    const float* wt_m = (m == 0) ? wqt : (m == 1) ? wkt : wvt;
    const float* b_m  = (m == 0) ? bq  : (m == 1) ? bk  : bv;
    float* out_m      = (m == 0) ? Q   : (m == 1) ? K   : V;
    float acc = b_m[d2];
    for (int ee = 0; ee < DIM; ee++) acc = fmaf(wt_m[ee*DIM + d2], sy[ee], acc);
    int h = d2 >> 4, dh = d2 & 15;
    out_m[((size_t)(b*HH + h)*NP + t)*DHH + dh] = fmaxf(acc, 0.f);
  }
}

// ---------------- conv2d weight prep (coalesced reads via LDS) ----------------
__global__ void k_wprep(const float* __restrict__ w, __bf16* __restrict__ wtb) {
  int l = blockIdx.x / C2, oc = blockIdx.x % C2;
  int tid = threadIdx.x;
  __shared__ float swt[C2*9];
  const float4* wsrc = (const float4*)(w + ((size_t)(l*C2 + oc))*C2*9);
  for (int idx = tid; idx < 576; idx += 256) ((float4*)swt)[idx] = wsrc[idx];
  __syncthreads();
  for (int v = tid; v < 288; v += 256) {
    int chunk = v / 18, rem = v % 18;
    int kk = rem >> 1, kh = rem & 1;
    Pack8 p;
    #pragma unroll
    for (int e = 0; e < 8; e++)
      p.h[e] = (__bf16)swt[(chunk*16 + kh*8 + e)*9 + kk];
    size_t unit = ((((size_t)(l*16 + chunk)*9 + kk)*2 + kh)*256 + oc);
    ((uint4*)wtb)[unit] = p.u;
  }
}

// ---------------- layer-0 conv input build from t-major sources; zeroes 3x STAT2 ----------------
__global__ void k_make_convin(const float* __restrict__ CcT, const float* __restrict__ CLT0,
                              __bf16* __restrict__ inb, float* __restrict__ STATALL) {
  int idx = blockIdx.x*256 + threadIdx.x;
  if (blockIdx.x == 0) {
    for (int z = threadIdx.x; z < 3*2*C2; z += 256) STATALL[z] = 0.f;
  }
  int kh = idx & 1;
  int t = idx >> 1;
  int gcol = t % PC; int t2 = t / PC;
  int grow = t2 % PR; int t3 = t2 / PR;
  int chunk = t3 & 15; int b = t3 >> 4;
  int i = grow - 1, j = gcol - 8;
  Pack8 p;
  if ((unsigned)i < 192u && (unsigned)j < 192u) {
    int cbase = chunk*16 + kh*8;
    const float* pa;
    const float* pb;
    if (cbase < DIM) {
      pa = CcT  + (size_t)(b*NP + i)*DIM + cbase;
      pb = CLT0 + (size_t)(b*NP + i)*DIM + cbase;
    } else {
      pa = CcT  + (size_t)(b*NP + j)*DIM + (cbase - DIM);
      pb = CLT0 + (size_t)(b*NP + j)*DIM + (cbase - DIM);
    }
    #pragma unroll
    for (int e = 0; e < 8; e++) p.h[e] = (__bf16)(pa[e] + pb[e]);
  } else {
    #pragma unroll
    for (int e = 0; e < 8; e++) p.h[e] = (__bf16)0.f;
  }
  ((uint4*)inb)[idx] = p.u;
}

// ---------------- heavy kernel: implicit-GEMM bf16 MFMA 3x3 conv ----------------
// grid (3 jt, 48 it, 8 = b*4+oct), block 256 (4 waves = 2 row-groups x 2 col-halves).
// Block tile: 64 oc x (4 rows x 64 cols); wave tile 64 oc x 2 rows x 32 cols.
// Per chunk per wave: 30 ds_read_b128 (4 B + 6 A per kj) for 36 MFMAs = 0.83 r/MFMA.
// Staging: W 1152 u + I 960 u (6 rows x 80 x 2kh) = 33.8 KB/buffer; dbuf 67.6 KB -> 2 blocks/CU.
__global__ __launch_bounds__(256, 2)
void k_conv2d_mfma(const __bf16* __restrict__ inb,   // padded [b][16][PR][PC][2][8]
                   const __bf16* __restrict__ wtb,   // [16][9][2][256][8] (layer slice)
                   __bf16* __restrict__ rawb,        // [b][32][192][192][8]
                   float* __restrict__ STAT2) {
  __shared__ __align__(16) uint4 sbuf[2*2112];       // 67584 B
  int tid = threadIdx.x;
  int jt = blockIdx.x, it = blockIdx.y, zz = blockIdx.z;
  int b = zz >> 2, oct = zz & 3;
  int i0 = it*4, j0 = jt*64, oc0 = oct*64;
  int lane = tid & 63, wv = tid >> 6;
  int wr = wv >> 1, wc = wv & 1;                     // row-group, col-half
  int ln31 = lane & 31, khl = lane >> 5;

  const uint4* gW = (const uint4*)wtb;
  const uint4* gI = (const uint4*)inb;

  f32x16 acc[2][2];   // [rr][om]
  #pragma unroll
  for (int r = 0; r < 2; r++)
    #pragma unroll
    for (int m = 0; m < 2; m++)
      #pragma unroll
      for (int q = 0; q < 16; q++) acc[r][m][q] = 0.f;

  // staging: 33 wave-segments of 64 lanes; this wave's slots L = t*4 + wv.
  // L 0..17 = W (1152 units); L 18..32 = I (960 units).
  const uint4* gp[9];
  int lofs[9];
  int gstride[9];
  bool gvalid[9];
  #pragma unroll
  for (int t = 0; t < 9; t++) {
    int L = t*4 + wv;
    gvalid[t] = (L < 33);
    if (L < 18) {                              // W segment
      int u = L*64 + lane;                     // 0..1151
      int kkh = u >> 6;                        // 0..17
      int ocl = u & 63;
      gp[t] = gW + (size_t)kkh*256 + oc0 + ocl;
      lofs[t] = u;
      gstride[t] = 4608;
    } else {                                   // I segment
      int u = (L - 18)*64 + lane;              // 0..959
      int r = u / 160;
      int rem = u % 160;
      int kh = rem / 80;
      int c = rem % 80;
      gp[t] = gI + (((size_t)(b*16)*PR) + i0 + r)*PC*2 + (size_t)(j0 + c)*2 + kh;
      lofs[t] = 1152 + u;
      gstride[t] = PR*PC*2;
    }
  }

  auto issue = [&](int buf) {
    uint4* lbase = sbuf + buf*2112;
    #pragma unroll
    for (int t = 0; t < 9; t++) {
      if (gvalid[t]) {
        GLOAD16(gp[t], lbase + lofs[t]);
        gp[t] += gstride[t];
      }
    }
  };

  issue(0);

  for (int chunk = 0; chunk < 16; ++chunk) {
    int buf = chunk & 1;
    __syncthreads();                   // staged data visible; prev buf's ds_reads done
    if (chunk < 15) issue(buf ^ 1);
    const __bf16* Wl = (const __bf16*)(sbuf + buf*2112);
    const __bf16* Il = (const __bf16*)(sbuf + buf*2112 + 1152);
    #pragma unroll
    for (int kj = 0; kj < 3; kj++) {
      // B fragments for staged rows wr*2 + rx (rx=0..3), this wave's col-half
      bf16x8 bfr[4];
      #pragma unroll
      for (int rx = 0; rx < 4; rx++) {
        int r = wr*2 + rx;
        int c = wc*32 + ln31 + kj + 7;
        bfr[rx] = *(const bf16x8*)(Il + ((r*2 + khl)*80 + c)*8);
      }
      #pragma unroll
      for (int ki = 0; ki < 3; ki++) {
        int kk = ki*3 + kj;
        bf16x8 a0 = *(const bf16x8*)(Wl + ((kk*2 + khl)*64 +      ln31)*8);
        bf16x8 a1 = *(const bf16x8*)(Wl + ((kk*2 + khl)*64 + 32 + ln31)*8);
        #pragma unroll
        for (int rr = 0; rr < 2; rr++) {
          acc[rr][0] = __builtin_amdgcn_mfma_f32_32x32x16_bf16(a0, bfr[rr + ki], acc[rr][0], 0, 0, 0);
          acc[rr][1] = __builtin_amdgcn_mfma_f32_32x32x16_bf16(a1, bfr[rr + ki], acc[rr][1], 0, 0, 0);
        }
      }
    }
  }

  __syncthreads();                     // all ds_reads done; overlay LDS for epilogue
  float* trAll = (float*)sbuf;
  float* tr = trAll + wv*(32*33);
  float* sstat = trAll + 4*32*33;      // 128 floats: [64 sum][64 sumsq]
  if (tid < 128) sstat[tid] = 0.f;
  __syncthreads();

  // fused BN2 partial stats (wave covers 64 oc x 2 rows x 32 cols)
  #pragma unroll
  for (int om = 0; om < 2; om++) {
    #pragma unroll
    for (int reg = 0; reg < 16; reg++) {
      float v0 = acc[0][om][reg], v1 = acc[1][om][reg];
      float s = v0 + v1, s2 = v0*v0 + v1*v1;
      #pragma unroll
      for (int msk = 1; msk <= 16; msk <<= 1) { s += __shfl_xor(s, msk); s2 += __shfl_xor(s2, msk); }
      if (ln31 == 0) {
        int oc_l = om*32 + (reg & 3) + 8*(reg >> 2) + 4*khl;
        atomicAdd(&sstat[oc_l], s);
        atomicAdd(&sstat[64 + oc_l], s2);
      }
    }
  }

  // packed bf16 output via wave-local LDS transpose
  uint4* RAWu = (uint4*)rawb;
  #pragma unroll
  for (int rr = 0; rr < 2; rr++) {
    int i = i0 + wr*2 + rr;
    #pragma unroll
    for (int om = 0; om < 2; om++) {
      int Gb = (oc0 + om*32) >> 3;
      #pragma unroll
      for (int reg = 0; reg < 16; reg++) {
        int r = (reg & 3) + 8*(reg >> 2) + 4*khl;
        tr[r*33 + ln31] = acc[rr][om][reg];
      }
      __builtin_amdgcn_s_waitcnt(0);
      #pragma unroll
      for (int gs = 0; gs < 2; gs++) {
        int g = khl + gs*2;
        Pack8 p;
        #pragma unroll
        for (int e = 0; e < 8; e++) p.h[e] = (__bf16)tr[(g*8 + e)*33 + ln31];
        RAWu[((size_t)(b*32 + Gb + g)*192 + i)*192 + j0 + wc*32 + ln31] = p.u;
      }
      __builtin_amdgcn_s_waitcnt(0);
    }
  }

  __syncthreads();
  if (tid < 64) {
    atomicAdd(&STAT2[oc0 + tid], sstat[tid]);
    atomicAdd(&STAT2[C2 + oc0 + tid], sstat[64 + tid]);
  }
}

// ---------------- fused: BN2 norm+relu, gate proj, next conv input: WIDER (768 thr) ----------------
template<int WRITE_NEXT>
__global__ __launch_bounds__(768)
void k_bn2_norm_gate(const __bf16* __restrict__ rawb, const float* __restrict__ STAT2,
                     const float* __restrict__ g, const float* __restrict__ bb,
                     const float* __restrict__ wd, const float* __restrict__ CLnT,
                     __bf16* __restrict__ inb_next, float* __restrict__ tg) {
  int i = blockIdx.x, b = blockIdx.y;
  int tid = threadIdx.x;
  int j = tid % 192, qt = tid / 192;       // quarter 0..3
  __shared__ float sscale[C2], sshift[C2], swd[HH*C2];
  __shared__ float sg[4][HH][192];
  const float inv = 1.f / (float)(BB*NN);
  for (int c = tid; c < C2; c += 768) {
    float mean = STAT2[c] * inv;
    float var  = STAT2[C2 + c] * inv - mean*mean;
    float rstd = rsqrtf(var + EPS);
    float sc = rstd * g[c];
    sscale[c] = sc;
    sshift[c] = bb[c] - mean*sc;
  }
  for (int idx = tid; idx < HH*C2; idx += 768) swd[idx] = wd[idx];
  __syncthreads();
  float gacc[HH] = {};
  const uint4* RAWu = (const uint4*)rawb;
  const float* clrow_i = CLnT ? CLnT + (size_t)(b*NP + i)*DIM : nullptr;
  const float* clrow_j = CLnT ? CLnT + (size_t)(b*NP + j)*DIM : nullptr;
  for (int cu = qt*8; cu < qt*8 + 8; cu++) {
    Pack8 pr; pr.u = RAWu[((size_t)(b*32 + cu)*NP + i)*NP + j];
    Pack8 p;
    int cbase = cu*8;
    const float* clp = (WRITE_NEXT && cbase < DIM) ? clrow_i + cbase
                     : (WRITE_NEXT ? clrow_j + (cbase - DIM) : nullptr);
    #pragma unroll
    for (int e = 0; e < 8; e++) {
      int c = cbase + e;
      float v = (float)pr.h[e];
      v = fmaxf(fmaf(v, sscale[c], sshift[c]), 0.f);
      if (WRITE_NEXT) p.h[e] = (__bf16)(v + clp[e]);
      #pragma unroll
      for (int h = 0; h < HH; h++) gacc[h] = fmaf(v, swd[h*C2 + c], gacc[h]);
    }
    if (WRITE_NEXT) {
      size_t unit = ((((size_t)(b*16 + (cu>>1))*PR + (i+1))*PC + (j+8))*2 + (cu&1));
      ((uint4*)inb_next)[unit] = p.u;
    }
  }
  #pragma unroll
  for (int h = 0; h < HH; h++) sg[qt][h][j] = gacc[h];
  __syncthreads();
  if (qt == 0) {
    #pragma unroll
    for (int h = 0; h < HH; h++)
      tg[((size_t)(b*HH + h)*NP + i)*NP + j] = sg[0][h][j] + sg[1][h][j] + sg[2][h][j] + sg[3][h][j];
  }
}

// ---------------- gate = sigmoid(t + t^T + bias), coalesced tiled transpose ----------------
__global__ void k_gate(const float* __restrict__ tg, const float* __restrict__ wdb,
                       float* __restrict__ gate) {
  int tile = blockIdx.x;
  int hb = blockIdx.y;
  int b = hb >> 3, h = hb & 7;
  size_t bh = (size_t)(b*HH + h);
  int ti = tile / 6, tj = tile % 6;
  int r = threadIdx.x >> 3, c4 = threadIdx.x & 7;
  __shared__ float tB[32][33];
  const float* base = tg + bh*NN;
  float4 vb = *(const float4*)(base + (tj*32 + r)*NP + ti*32 + c4*4);
  tB[r][c4*4+0] = vb.x; tB[r][c4*4+1] = vb.y; tB[r][c4*4+2] = vb.z; tB[r][c4*4+3] = vb.w;
  __syncthreads();
  float4 va = *(const float4*)(base + (ti*32 + r)*NP + tj*32 + c4*4);
  float bias = wdb[h];
  float4 o;
  o.x = 1.f / (1.f + expf(-(va.x + tB[c4*4+0][r] + bias)));
  o.y = 1.f / (1.f + expf(-(va.y + tB[c4*4+1][r] + bias)));
  o.z = 1.f / (1.f + expf(-(va.z + tB[c4*4+2][r] + bias)));
  o.w = 1.f / (1.f + expf(-(va.w + tB[c4*4+3][r] + bias)));
  *(float4*)(gate + bh*NN + (ti*32 + r)*NP + tj*32 + c4*4) = o;
}

// ---------------- MEGA-fused attnx: WIDE (384 thr), t-major ccn ----------------
template<int MODE>
__global__ __launch_bounds__(384)
void k_attnx(const float* __restrict__ Q, const float* __restrict__ K,
             const float* __restrict__ V, const float* __restrict__ gate,
             const float* __restrict__ mask,
             float* __restrict__ X,
             const float* __restrict__ wlt, const float* __restrict__ bl,
             const float* __restrict__ ccnT,
             const float* __restrict__ lng, const float* __restrict__ lnb,
             const float* __restrict__ wqt, const float* __restrict__ bq,
             const float* __restrict__ wkt, const float* __restrict__ bk,
             const float* __restrict__ wvt, const float* __restrict__ bv,
             float* __restrict__ Qn, float* __restrict__ Kn, float* __restrict__ Vn,
             const float* __restrict__ fct, const float* __restrict__ fb,
             float* __restrict__ out) {
  int i = blockIdx.x, b = blockIdx.y;
  int tid = threadIdx.x;
  int j = tid % 192, half = tid / 192;
  int lane = tid & 63, wave = tid >> 6;
  __shared__ float sq[DIM];
  __shared__ float sattn[HH][NP];
  __shared__ float spv[3][DIM];
  __shared__ float supd[DIM];
  __shared__ float sy[DIM];
  __shared__ float sxp[3][DIM];
  __shared__ float sredm[HH][3];
  __shared__ float sreds[HH][3];
  __shared__ float sred[2];
  float mk = mask[b*NP + j];

  if (tid < DIM) {
    int h = tid >> 4, d = tid & 15;
    sq[tid] = Q[(((size_t)(b*HH + h))*NP + i)*DHH + d];
  }
  __syncthreads();

  float a[4], gt[4];
  #pragma unroll
  for (int hh = 0; hh < 4; hh++) {
    int h = half*4 + hh;
    size_t bh = (size_t)(b*HH + h);
    const float4* kr = (const float4*)(K + (bh*NP + j)*DHH);
    const float4* qr = (const float4*)(sq + h*DHH);
    float acc = 0.f;
    #pragma unroll
    for (int q4 = 0; q4 < 4; q4++) {
      float4 qv = qr[q4], kv = kr[q4];
      acc = fmaf(qv.x, kv.x, acc); acc = fmaf(qv.y, kv.y, acc);
      acc = fmaf(qv.z, kv.z, acc); acc = fmaf(qv.w, kv.w, acc);
    }
    a[hh] = acc * 0.25f;
    gt[hh] = gate[(bh*NP + i)*NP + j];
  }
  #pragma unroll
  for (int hh = 0; hh < 4; hh++) {
    int h = half*4 + hh;
    float m = a[hh];
    #pragma unroll
    for (int s = 32; s > 0; s >>= 1) m = fmaxf(m, __shfl_xor(m, s));
    if (lane == 0) sredm[h][wave % 3] = m;
  }
  __syncthreads();
  float e[4];
  #pragma unroll
  for (int hh = 0; hh < 4; hh++) {
    int h = half*4 + hh;
    float amax = fmaxf(fmaxf(sredm[h][0], sredm[h][1]), sredm[h][2]);
    e[hh] = expf(a[hh] - amax) * mk;
    float ss = e[hh];
    #pragma unroll
    for (int s = 32; s > 0; s >>= 1) ss += __shfl_xor(ss, s);
    if (lane == 0) sreds[h][wave % 3] = ss;
  }
  __syncthreads();
  #pragma unroll
  for (int hh = 0; hh < 4; hh++) {
    int h = half*4 + hh;
    float denom = sreds[h][0] + sreds[h][1] + sreds[h][2] + 1e-6f;
    sattn[h][j] = (e[hh] / denom) * gt[hh];
  }
  __syncthreads();

  {
    int d = tid & 15, h2 = (tid >> 4) & 7, jseg = tid >> 7;
    size_t bh = (size_t)(b*HH + h2);
    float acc = 0.f;
    for (int jj = jseg*64; jj < jseg*64 + 64; jj++)
      acc = fmaf(sattn[h2][jj], V[(bh*NP + jj)*DHH + d], acc);
    spv[jseg][h2*DHH + d] = acc;
  }
  __syncthreads();
  if (tid < DIM) supd[tid] = spv[0][tid] + spv[1][tid] + spv[2][tid];
  __syncthreads();

  size_t o = (size_t)(b*NP + i)*DIM;
  if (tid < DIM) sy[tid] = X[o + tid] + supd[tid];
  __syncthreads();
  {
    int d2 = tid & 127, ks = tid >> 7;
    int e0 = ks*43, e1 = (ks == 2) ? 128 : e0 + 43;
    float acc = (ks == 0) ? bl[d2] : 0.f;
    for (int ee = e0; ee < e1; ee++) acc = fmaf(wlt[ee*DIM + d2], sy[ee], acc);
    sxp[ks][d2] = acc;
  }
  __syncthreads();
  float xr = 0.f;
  if (tid < DIM) xr = fmaxf(sxp[0][tid] + sxp[1][tid] + sxp[2][tid], 0.f);
  __syncthreads();

  if (MODE == 0) {
    float v = 0.f;
    if (tid < DIM) v = xr + ccnT[o + tid];
    if (tid < DIM) {
      float s = v;
      #pragma unroll
      for (int m = 32; m > 0; m >>= 1) s += __shfl_xor(s, m);
      if (lane == 0) sred[wave] = s;
    }
    __syncthreads();
    float mean = (sred[0] + sred[1]) * (1.f/128.f);
    float dv = v - mean;
    __syncthreads();
    if (tid < DIM) {
      float q = dv*dv;
      #pragma unroll
      for (int m = 32; m > 0; m >>= 1) q += __shfl_xor(q, m);
      if (lane == 0) sred[wave] = q;
    }
    __syncthreads();
    float var = (sred[0] + sred[1]) * (1.f/128.f);
    float rstd = rsqrtf(var + EPS);
    if (tid < DIM) {
      float xn = dv * rstd * lng[tid] + lnb[tid];
      X[o + tid] = xn;
      sy[tid] = xn;
    }
    __syncthreads();
    {
      int d2 = tid & 127, m = tid >> 7;
      const float* wt_m = (m == 0) ? wqt : (m == 1) ? wkt : wvt;
      const float* b_m  = (m == 0) ? bq  : (m == 1) ? bk  : bv;
      float* out_m      = (m == 0) ? Qn  : (m == 1) ? Kn  : Vn;
      float acc = b_m[d2];
      for (int ee = 0; ee < DIM; ee++) acc = fmaf(wt_m[ee*DIM + d2], sy[ee], acc);
      int h = d2 >> 4, dh = d2 & 15;
      out_m[((size_t)(b*HH + h)*NP + i)*DHH + dh] = fmaxf(acc, 0.f);
    }
  } else {
    if (tid < DIM) sy[tid] = xr;
    __syncthreads();
    {
      int d2 = tid & 127, ks = tid >> 7;
      int e0 = ks*43, e1 = (ks == 2) ? 128 : e0 + 43;
      float acc = (ks == 0) ? fb[d2] : 0.f;
      for (int ee = e0; ee < e1; ee++) acc = fmaf(fct[ee*DIM + d2], sy[ee], acc);
      sxp[ks][d2] = acc;
    }
    __syncthreads();
    if (tid < DIM)
      out[o + tid] = fmaxf(sxp[0][tid] + sxp[1][tid] + sxp[2][tid], 0.f);
  }
}

extern "C" void kernel_launch(void* const* d_in, const int* in_sizes, int n_in,
                              void* d_out, int out_size, void* d_ws, size_t ws_size,
                              hipStream_t stream) {
  const float* seq     = (const float*)d_in[0];
  const float* mask    = (const float*)d_in[1];
  const float* conv1_w = (const float*)d_in[2];
  const float* conv2_w = (const float*)d_in[3];
  const float* ln_g    = (const float*)d_in[4];
  const float* ln_b    = (const float*)d_in[5];
  const float* c1d_w   = (const float*)d_in[6];
  const float* bn1_g   = (const float*)d_in[7];
  const float* bn1_b   = (const float*)d_in[8];
  const float* c2d_w   = (const float*)d_in[9];
  const float* bn2_g   = (const float*)d_in[10];
  const float* bn2_b   = (const float*)d_in[11];
  const float* wq_w    = (const float*)d_in[12];
  const float* wq_b    = (const float*)d_in[13];
  const float* wk_w    = (const float*)d_in[14];
  const float* wk_b    = (const float*)d_in[15];
  const float* wv_w    = (const float*)d_in[16];
  const float* wv_b    = (const float*)d_in[17];
  const float* wd_w    = (const float*)d_in[18];
  const float* wd_b    = (const float*)d_in[19];
  const float* wl_w    = (const float*)d_in[20];
  const float* wl_b    = (const float*)d_in[21];
  const float* fc_w    = (const float*)d_in[22];
  const float* fc_b    = (const float*)d_in[23];
  float* out = (float*)d_out;

  float* ws = (float*)d_ws;
  float* X    = ws; ws += BB*NP*DIM;
  float* Cc   = ws; ws += BB*DIM*NP;
  float* CcT  = ws; ws += BB*DIM*NP;
  float* CL0  = ws; ws += BB*DIM*NP;
  float* CL1  = ws; ws += BB*DIM*NP;
  float* CL2  = ws; ws += BB*DIM*NP;
  float* CLT0 = ws; ws += BB*DIM*NP;
  float* CLT1 = ws; ws += BB*DIM*NP;
  float* CLT2 = ws; ws += BB*DIM*NP;
  float* Q0   = ws; ws += BB*NP*DIM;
  float* K0   = ws; ws += BB*NP*DIM;
  float* V0   = ws; ws += BB*NP*DIM;
  float* Q1   = ws; ws += BB*NP*DIM;
  float* K1   = ws; ws += BB*NP*DIM;
  float* V1   = ws; ws += BB*NP*DIM;
  float* TG   = ws; ws += (size_t)BB*HH*NN;
  float* GATE = ws; ws += (size_t)BB*HH*NN;
  float* WQT  = ws; ws += (size_t)LL*DIM*DIM;
  float* WKT  = ws; ws += (size_t)LL*DIM*DIM;
  float* WVT  = ws; ws += (size_t)LL*DIM*DIM;
  float* WLT  = ws; ws += (size_t)LL*DIM*DIM;
  float* FCT  = ws; ws += (size_t)DIM*DIM;
  float* STATALL = ws; ws += 3*2*C2;
  __bf16* RAW = (__bf16*)ws; ws += (size_t)BB*C2*NN/2;
  __bf16* INB = (__bf16*)ws; ws += (size_t)BB*16*PR*PC*2*16/4;
  __bf16* WTB = (__bf16*)ws; ws += (size_t)LL*C2*C2*9/2;

  k_wtrans<<<dim3(16, 13), 256, 0, stream>>>(wq_w, wk_w, wv_w, wl_w, fc_w,
                                             WQT, WKT, WVT, WLT, FCT);
  k_wprep<<<LL*C2, 256, 0, stream>>>(c2d_w, WTB);
  k_conv_init<<<dim3(NP, BB), DIM, 0, stream>>>(seq, conv1_w, conv2_w, X, Cc, CcT);
  k_conv1d_bn_relu<<<DIM, 768, 0, stream>>>(Cc,  c1d_w + 0*(size_t)DIM*DIM*3, bn1_g + 0*DIM, bn1_b + 0*DIM, CL0, CLT0);
  k_conv1d_bn_relu<<<DIM, 768, 0, stream>>>(CL0, c1d_w + 1*(size_t)DIM*DIM*3, bn1_g + 1*DIM, bn1_b + 1*DIM, CL1, CLT1);
  k_conv1d_bn_relu<<<DIM, 768, 0, stream>>>(CL1, c1d_w + 2*(size_t)DIM*DIM*3, bn1_g + 2*DIM, bn1_b + 2*DIM, CL2, CLT2);
  k_make_convin<<<(BB*16*PR*PC*2)/256, 256, 0, stream>>>(CcT, CLT0, INB, STATALL);
  k_lnqkv<<<dim3(NP, BB), 384, 0, stream>>>(X, CLT0, ln_g, ln_b,
                                            WQT, wq_b, WKT, wk_b, WVT, wv_b, Q0, K0, V0);

  // ---- layer 0 ----
  k_conv2d_mfma<<<dim3(3, 48, 8), 256, 0, stream>>>(INB, WTB + 0*(size_t)16*9*2*256*8, RAW, STATALL + 0*2*C2);
  k_bn2_norm_gate<1><<<dim3(NP, BB), 768, 0, stream>>>(RAW, STATALL + 0*2*C2, bn2_g + 0*C2, bn2_b + 0*C2,
                                                       wd_w + 0*(size_t)HH*C2, CLT1, INB, TG);
  k_gate<<<dim3(36, 16), 256, 0, stream>>>(TG, wd_b + 0*HH, GATE);
  k_attnx<0><<<dim3(NP, BB), 384, 0, stream>>>(Q0, K0, V0, GATE, mask, X,
                                               WLT + 0*(size_t)DIM*DIM, wl_b + 0*DIM,
                                               CLT1, ln_g + 1*DIM, ln_b + 1*DIM,
                                               WQT + 1*(size_t)DIM*DIM, wq_b + 1*DIM,
                                               WKT + 1*(size_t)DIM*DIM, wk_b + 1*DIM,
                                               WVT + 1*(size_t)DIM*DIM, wv_b + 1*DIM,
                                               Q1, K1, V1, nullptr, nullptr, nullptr);
  // ---- layer 1 ----
  k_conv2d_mfma<<<dim3(3, 48, 8), 256, 0, stream>>>(INB, WTB + 1*(size_t)16*9*2*256*8, RAW, STATALL + 1*2*C2);
  k_bn2_norm_gate<1><<<dim3(NP, BB), 768, 0, stream>>>(RAW, STATALL + 1*2*C2, bn2_g + 1*C2, bn2_b + 1*C2,
                                                       wd_w + 1*(size_t)HH*C2, CLT2, INB, TG);
  k_gate<<<dim3(36, 16), 256, 0, stream>>>(TG, wd_b + 1*HH, GATE);
  k_attnx<0><<<dim3(NP, BB), 384, 0, stream>>>(Q1, K1, V1, GATE, mask, X,
                                               WLT + 1*(size_t)DIM*DIM, wl_b + 1*DIM,
                                               CLT2, ln_g + 2*DIM, ln_b + 2*DIM,
                                               WQT + 2*(size_t)DIM*DIM, wq_b + 2*DIM,
                                               WKT + 2*(size_t)DIM*DIM, wk_b + 2*DIM,
                                               WVT + 2*(size_t)DIM*DIM, wv_b + 2*DIM,
                                               Q0, K0, V0, nullptr, nullptr, nullptr);
  // ---- layer 2 ----
  k_conv2d_mfma<<<dim3(3, 48, 8), 256, 0, stream>>>(INB, WTB + 2*(size_t)16*9*2*256*8, RAW, STATALL + 2*2*C2);
  k_bn2_norm_gate<0><<<dim3(NP, BB), 768, 0, stream>>>(RAW, STATALL + 2*2*C2, bn2_g + 2*C2, bn2_b + 2*C2,
                                                       wd_w + 2*(size_t)HH*C2, nullptr, nullptr, TG);
  k_gate<<<dim3(36, 16), 256, 0, stream>>>(TG, wd_b + 2*HH, GATE);
  k_attnx<1><<<dim3(NP, BB), 384, 0, stream>>>(Q0, K0, V0, GATE, mask, X,
                                               WLT + 2*(size_t)DIM*DIM, wl_b + 2*DIM,
                                               nullptr, nullptr, nullptr,
                                               nullptr, nullptr, nullptr, nullptr, nullptr, nullptr,
                                               nullptr, nullptr, nullptr,
                                               FCT, fc_b, out);
}

// Round 14
// 579.513 us; speedup vs baseline: 1.1641x; 1.0618x over previous
//
#include <hip/hip_runtime.h>
#include <math.h>

#define IN_DIM 20
#define DIM 128
#define HH 8
#define LL 3
#define BB 2
#define NP 192
#define DHH 16
#define C2 256
#define NN (NP*NP)
#define EPS 1e-5f

// padded conv-input geometry
#define PR 200
#define PC 224

typedef __bf16 bf16x8 __attribute__((ext_vector_type(8)));
typedef float  f32x16 __attribute__((ext_vector_type(16)));

union Pack8 { __bf16 h[8]; uint4 u; };

#define GLOAD16(gp, lp) \
  __builtin_amdgcn_global_load_lds((const __attribute__((address_space(1))) uint4*)(gp), \
                                   (__attribute__((address_space(3))) uint4*)(lp), 16, 0, 0)

// ---------------- init: conv1d over seq for both x and c (+ t-major CcT) ----------------
__global__ void k_conv_init(const float* __restrict__ seq, const float* __restrict__ w1,
                            const float* __restrict__ w2, float* __restrict__ X,
                            float* __restrict__ Cc, float* __restrict__ CcT) {
  int t = blockIdx.x, b = blockIdx.y, oc = threadIdx.x;
  __shared__ float ss[3][IN_DIM];
  if (threadIdx.x < 3*IN_DIM) {
    int k = threadIdx.x / IN_DIM, ic = threadIdx.x % IN_DIM;
    int tt = t + k - 1;
    ss[k][ic] = (tt >= 0 && tt < NP) ? seq[(b*NP + tt)*IN_DIM + ic] : 0.f;
  }
  __syncthreads();
  float a1 = 0.f, a2 = 0.f;
  #pragma unroll
  for (int ic = 0; ic < IN_DIM; ic++) {
    #pragma unroll
    for (int k = 0; k < 3; k++) {
      float sv = ss[k][ic];
      a1 = fmaf(w1[(oc*IN_DIM + ic)*3 + k], sv, a1);
      a2 = fmaf(w2[(oc*IN_DIM + ic)*3 + k], sv, a2);
    }
  }
  X[(b*NP + t)*DIM + oc] = a1;
  Cc[(b*DIM + oc)*NP + t] = a2;
  CcT[(size_t)(b*NP + t)*DIM + oc] = a2;
}

// ---------------- conv1d + BN + relu: WIDE (768 thr); writes c-major AND t-major ----------------
__global__ __launch_bounds__(768)
void k_conv1d_bn_relu(const float* __restrict__ cin, const float* __restrict__ w,
                      const float* __restrict__ g, const float* __restrict__ bb,
                      float* __restrict__ cout, float* __restrict__ coutT) {
  int oc = blockIdx.x;
  int tid = threadIdx.x;
  int t = tid % NP;
  int sub = tid / NP;            // 0..3
  int b = sub & 1, ih = sub >> 1;
  float acc = 0.f;
  for (int ic = ih*64; ic < ih*64 + 64; ic++) {
    const float* cr = cin + (b*DIM + ic)*NP;
    const float* wr = w + (oc*DIM + ic)*3;
    float lf = (t > 0)      ? cr[t-1] : 0.f;
    float mf = cr[t];
    float rf = (t < NP-1)   ? cr[t+1] : 0.f;
    acc = fmaf(lf, wr[0], acc);
    acc = fmaf(mf, wr[1], acc);
    acc = fmaf(rf, wr[2], acc);
  }
  __shared__ float sp[4][NP];
  __shared__ float sb[768];
  sp[sub][t] = acc;
  __syncthreads();
  float raw = sp[b][t] + sp[2 + b][t];
  sb[tid] = (sub < 2) ? raw : raw * raw;
  __syncthreads();
  for (int s = 192; s >= 3; s >>= 1) {
    if (tid < s) sb[tid] += sb[tid + s];
    int u = tid - 384;
    if (u >= 0 && u < s) sb[tid] += sb[tid + s];
    __syncthreads();
  }
  float mean = (sb[0] + sb[1] + sb[2]) / 384.f;
  float var  = (sb[384] + sb[385] + sb[386]) / 384.f - mean*mean;
  float rstd = rsqrtf(var + EPS);
  if (sub < 2) {
    float v = fmaxf((raw - mean)*rstd*g[oc] + bb[oc], 0.f);
    cout[(b*DIM + oc)*NP + t] = v;
    coutT[(size_t)(b*NP + t)*DIM + oc] = v;
  }
}

// ---------------- small-weight transpose: wT[e][j] = w[j][e], 13 matrices ----------------
__global__ void k_wtrans(const float* __restrict__ wq, const float* __restrict__ wk,
                         const float* __restrict__ wv, const float* __restrict__ wl,
                         const float* __restrict__ fcw,
                         float* __restrict__ wqt, float* __restrict__ wkt,
                         float* __restrict__ wvt, float* __restrict__ wlt,
                         float* __restrict__ fct) {
  int m = blockIdx.y;
  const float* src; float* dst;
  if (m < 3)       { src = wq + (size_t)m*DIM*DIM;     dst = wqt + (size_t)m*DIM*DIM; }
  else if (m < 6)  { src = wk + (size_t)(m-3)*DIM*DIM; dst = wkt + (size_t)(m-3)*DIM*DIM; }
  else if (m < 9)  { src = wv + (size_t)(m-6)*DIM*DIM; dst = wvt + (size_t)(m-6)*DIM*DIM; }
  else if (m < 12) { src = wl + (size_t)(m-9)*DIM*DIM; dst = wlt + (size_t)(m-9)*DIM*DIM; }
  else             { src = fcw;                        dst = fct; }
  int tile = blockIdx.x;
  int ti = tile >> 2, tj = tile & 3;
  int r = threadIdx.x >> 3, c4 = threadIdx.x & 7;
  __shared__ float t[32][33];
  float4 v = *(const float4*)(src + (ti*32 + r)*DIM + tj*32 + c4*4);
  t[r][c4*4+0] = v.x; t[r][c4*4+1] = v.y; t[r][c4*4+2] = v.z; t[r][c4*4+3] = v.w;
  __syncthreads();
  float4 o;
  o.x = t[c4*4+0][r]; o.y = t[c4*4+1][r]; o.z = t[c4*4+2][r]; o.w = t[c4*4+3][r];
  *(float4*)(dst + (tj*32 + r)*DIM + ti*32 + c4*4) = o;
}

// ---------------- layer-0: x = LN(x + ccT), q,k,v — WIDE (384 thr) ----------------
__global__ __launch_bounds__(384)
void k_lnqkv(float* __restrict__ X, const float* __restrict__ ccT,
             const float* __restrict__ g, const float* __restrict__ bb,
             const float* __restrict__ wqt, const float* __restrict__ bq,
             const float* __restrict__ wkt, const float* __restrict__ bk,
             const float* __restrict__ wvt, const float* __restrict__ bv,
             float* __restrict__ Q, float* __restrict__ K, float* __restrict__ V) {
  int t = blockIdx.x, b = blockIdx.y;
  int tid = threadIdx.x;
  int lane = tid & 63, wave = tid >> 6;
  __shared__ float sy[DIM];
  __shared__ float sred[2];
  size_t o = (size_t)(b*NP + t)*DIM;
  float v = 0.f;
  if (tid < DIM) v = X[o + tid] + ccT[o + tid];
  if (tid < DIM) {
    float s = v;
    #pragma unroll
    for (int m = 32; m > 0; m >>= 1) s += __shfl_xor(s, m);
    if (lane == 0) sred[wave] = s;
  }
  __syncthreads();
  float mean = (sred[0] + sred[1]) * (1.f/128.f);
  float dv = v - mean;
  __syncthreads();                     // all mean reads done before sred reuse
  if (tid < DIM) {
    float q = dv*dv;
    #pragma unroll
    for (int m = 32; m > 0; m >>= 1) q += __shfl_xor(q, m);
    if (lane == 0) sred[wave] = q;
  }
  __syncthreads();
  float var = (sred[0] + sred[1]) * (1.f/128.f);
  float rstd = rsqrtf(var + EPS);
  if (tid < DIM) {
    float xn = dv * rstd * g[tid] + bb[tid];
    X[o + tid] = xn;
    sy[tid] = xn;
  }
  __syncthreads();
  {
    int d2 = tid & 127, m = tid >> 7;
    const float* wt_m = (m == 0) ? wqt : (m == 1) ? wkt : wvt;
    const float* b_m  = (m == 0) ? bq  : (m == 1) ? bk  : bv;
    float* out_m      = (m == 0) ? Q   : (m == 1) ? K   : V;
    float acc = b_m[d2];
    for (int ee = 0; ee < DIM; ee++) acc = fmaf(wt_m[ee*DIM + d2], sy[ee], acc);
    int h = d2 >> 4, dh = d2 & 15;
    out_m[((size_t)(b*HH + h)*NP + t)*DHH + dh] = fmaxf(acc, 0.f);
  }
}

// ---------------- conv2d weight prep (coalesced reads via LDS) ----------------
__global__ void k_wprep(const float* __restrict__ w, __bf16* __restrict__ wtb) {
  int l = blockIdx.x / C2, oc = blockIdx.x % C2;
  int tid = threadIdx.x;
  __shared__ float swt[C2*9];
  const float4* wsrc = (const float4*)(w + ((size_t)(l*C2 + oc))*C2*9);
  for (int idx = tid; idx < 576; idx += 256) ((float4*)swt)[idx] = wsrc[idx];
  __syncthreads();
  for (int v = tid; v < 288; v += 256) {
    int chunk = v / 18, rem = v % 18;
    int kk = rem >> 1, kh = rem & 1;
    Pack8 p;
    #pragma unroll
    for (int e = 0; e < 8; e++)
      p.h[e] = (__bf16)swt[(chunk*16 + kh*8 + e)*9 + kk];
    size_t unit = ((((size_t)(l*16 + chunk)*9 + kk)*2 + kh)*256 + oc);
    ((uint4*)wtb)[unit] = p.u;
  }
}

// ---------------- layer-0 conv input build from t-major sources; zeroes 3x STAT2 ----------------
__global__ void k_make_convin(const float* __restrict__ CcT, const float* __restrict__ CLT0,
                              __bf16* __restrict__ inb, float* __restrict__ STATALL) {
  int idx = blockIdx.x*256 + threadIdx.x;
  if (blockIdx.x == 0) {
    for (int z = threadIdx.x; z < 3*2*C2; z += 256) STATALL[z] = 0.f;
  }
  int kh = idx & 1;
  int t = idx >> 1;
  int gcol = t % PC; int t2 = t / PC;
  int grow = t2 % PR; int t3 = t2 / PR;
  int chunk = t3 & 15; int b = t3 >> 4;
  int i = grow - 1, j = gcol - 8;
  Pack8 p;
  if ((unsigned)i < 192u && (unsigned)j < 192u) {
    int cbase = chunk*16 + kh*8;
    const float* pa;
    const float* pb;
    if (cbase < DIM) {
      pa = CcT  + (size_t)(b*NP + i)*DIM + cbase;
      pb = CLT0 + (size_t)(b*NP + i)*DIM + cbase;
    } else {
      pa = CcT  + (size_t)(b*NP + j)*DIM + (cbase - DIM);
      pb = CLT0 + (size_t)(b*NP + j)*DIM + (cbase - DIM);
    }
    #pragma unroll
    for (int e = 0; e < 8; e++) p.h[e] = (__bf16)(pa[e] + pb[e]);
  } else {
    #pragma unroll
    for (int e = 0; e < 8; e++) p.h[e] = (__bf16)0.f;
  }
  ((uint4*)inb)[idx] = p.u;
}

// ---------------- heavy kernel: implicit-GEMM bf16 MFMA 3x3 conv (R8 config — best) ----------------
// grid (3 jt, 24 it, 16 = b*8+oct), block 256 (4 waves).
// Block tile: 32 oc x (8 rows x 64 cols); wave tile 32 oc x 2 rows x 64 cols.
// Per chunk per wave: 33 ds_read_b128 for 36 MFMAs (0.92 r/MFMA).
// Staging: W 576 u + I 1600 u = 34.8 KB/buffer, dbuf -> 2 blocks/CU.
__global__ __launch_bounds__(256, 2)
void k_conv2d_mfma(const __bf16* __restrict__ inb,
                   const __bf16* __restrict__ wtb,
                   __bf16* __restrict__ rawb,
                   float* __restrict__ STAT2) {
  __shared__ __align__(16) uint4 sbuf[2*2176];       // 69632 B
  int tid = threadIdx.x;
  int jt = blockIdx.x, it = blockIdx.y, zz = blockIdx.z;
  int b = zz >> 3, oct = zz & 7;
  int i0 = it*8, j0 = jt*64, oc0 = oct*32;
  int lane = tid & 63, wv = tid >> 6;
  int ln31 = lane & 31, khl = lane >> 5;

  const uint4* gW = (const uint4*)wtb;
  const uint4* gI = (const uint4*)inb;

  f32x16 acc[2][2];   // [row][ch]
  #pragma unroll
  for (int r = 0; r < 2; r++)
    #pragma unroll
    for (int n = 0; n < 2; n++)
      #pragma unroll
      for (int q = 0; q < 16; q++) acc[r][n][q] = 0.f;

  const uint4* gp[9];
  int lofs[9];
  int gstride[9];
  bool gvalid[9];
  #pragma unroll
  for (int t = 0; t < 9; t++) {
    int L = t*4 + wv;
    gvalid[t] = (L < 34);
    if (L < 9) {
      int u = L*64 + lane;
      int kkh = u >> 5;
      int ocl = u & 31;
      gp[t] = gW + (size_t)kkh*256 + oc0 + ocl;
      lofs[t] = u;
      gstride[t] = 4608;
    } else {
      int u = L*64 + lane - 576;
      int r = u / 160;
      int rem = u % 160;
      int kh = rem / 80;
      int c = rem % 80;
      gp[t] = gI + (((size_t)(b*16)*PR) + i0 + r)*PC*2 + (size_t)(j0 + c)*2 + kh;
      lofs[t] = 576 + u;
      gstride[t] = PR*PC*2;
    }
  }

  auto issue = [&](int buf) {
    uint4* lbase = sbuf + buf*2176;
    #pragma unroll
    for (int t = 0; t < 9; t++) {
      if (gvalid[t]) {
        GLOAD16(gp[t], lbase + lofs[t]);
        gp[t] += gstride[t];
      }
    }
  };

  issue(0);

  for (int chunk = 0; chunk < 16; ++chunk) {
    int buf = chunk & 1;
    __syncthreads();
    if (chunk < 15) issue(buf ^ 1);
    const __bf16* Wl = (const __bf16*)(sbuf + buf*2176);
    const __bf16* Il = (const __bf16*)(sbuf + buf*2176 + 576);
    #pragma unroll
    for (int kj = 0; kj < 3; kj++) {
      bf16x8 bfr[4][2];
      #pragma unroll
      for (int rr = 0; rr < 4; rr++) {
        int r = wv*2 + rr;
        #pragma unroll
        for (int ch = 0; ch < 2; ch++) {
          int c = ch*32 + ln31 + kj + 7;
          bfr[rr][ch] = *(const bf16x8*)(Il + ((r*2 + khl)*80 + c)*8);
        }
      }
      #pragma unroll
      for (int ki = 0; ki < 3; ki++) {
        int kk = ki*3 + kj;
        bf16x8 a = *(const bf16x8*)(Wl + ((kk*2 + khl)*32 + ln31)*8);
        #pragma unroll
        for (int row = 0; row < 2; row++)
          #pragma unroll
          for (int ch = 0; ch < 2; ch++)
            acc[row][ch] = __builtin_amdgcn_mfma_f32_32x32x16_bf16(a, bfr[row + ki][ch], acc[row][ch], 0, 0, 0);
      }
    }
  }

  __syncthreads();
  float* trAll = (float*)sbuf;
  float* tr = trAll + wv*(32*33);
  float* sstat = trAll + 4*32*33;
  if (tid < 64) sstat[tid] = 0.f;
  __syncthreads();

  #pragma unroll
  for (int reg = 0; reg < 16; reg++) {
    float v00 = acc[0][0][reg], v01 = acc[0][1][reg];
    float v10 = acc[1][0][reg], v11 = acc[1][1][reg];
    float s = v00 + v01 + v10 + v11;
    float s2 = v00*v00 + v01*v01 + v10*v10 + v11*v11;
    #pragma unroll
    for (int msk = 1; msk <= 16; msk <<= 1) { s += __shfl_xor(s, msk); s2 += __shfl_xor(s2, msk); }
    if (ln31 == 0) {
      int oc_l = (reg & 3) + 8*(reg >> 2) + 4*khl;
      atomicAdd(&sstat[oc_l], s);
      atomicAdd(&sstat[32 + oc_l], s2);
    }
  }

  int Gb = oc0 >> 3;
  uint4* RAWu = (uint4*)rawb;
  #pragma unroll
  for (int row = 0; row < 2; row++) {
    int i = i0 + wv*2 + row;
    #pragma unroll
    for (int ch = 0; ch < 2; ch++) {
      #pragma unroll
      for (int reg = 0; reg < 16; reg++) {
        int r = (reg & 3) + 8*(reg >> 2) + 4*khl;
        tr[r*33 + ln31] = acc[row][ch][reg];
      }
      __builtin_amdgcn_s_waitcnt(0);
      #pragma unroll
      for (int gs = 0; gs < 2; gs++) {
        int g = khl + gs*2;
        Pack8 p;
        #pragma unroll
        for (int e = 0; e < 8; e++) p.h[e] = (__bf16)tr[(g*8 + e)*33 + ln31];
        RAWu[((size_t)(b*32 + Gb + g)*192 + i)*192 + j0 + ch*32 + ln31] = p.u;
      }
      __builtin_amdgcn_s_waitcnt(0);
    }
  }

  __syncthreads();
  if (tid < 32) {
    atomicAdd(&STAT2[oc0 + tid], sstat[tid]);
    atomicAdd(&STAT2[C2 + oc0 + tid], sstat[32 + tid]);
  }
}

// ---------------- fused: BN2 norm+relu, gate proj, next conv input: WIDER (768 thr) ----------------
template<int WRITE_NEXT>
__global__ __launch_bounds__(768)
void k_bn2_norm_gate(const __bf16* __restrict__ rawb, const float* __restrict__ STAT2,
                     const float* __restrict__ g, const float* __restrict__ bb,
                     const float* __restrict__ wd, const float* __restrict__ CLnT,
                     __bf16* __restrict__ inb_next, float* __restrict__ tg) {
  int i = blockIdx.x, b = blockIdx.y;
  int tid = threadIdx.x;
  int j = tid % 192, qt = tid / 192;       // quarter 0..3
  __shared__ float sscale[C2], sshift[C2], swd[HH*C2];
  __shared__ float sg[4][HH][192];
  const float inv = 1.f / (float)(BB*NN);
  for (int c = tid; c < C2; c += 768) {
    float mean = STAT2[c] * inv;
    float var  = STAT2[C2 + c] * inv - mean*mean;
    float rstd = rsqrtf(var + EPS);
    float sc = rstd * g[c];
    sscale[c] = sc;
    sshift[c] = bb[c] - mean*sc;
  }
  for (int idx = tid; idx < HH*C2; idx += 768) swd[idx] = wd[idx];
  __syncthreads();
  float gacc[HH] = {};
  const uint4* RAWu = (const uint4*)rawb;
  const float* clrow_i = CLnT ? CLnT + (size_t)(b*NP + i)*DIM : nullptr;
  const float* clrow_j = CLnT ? CLnT + (size_t)(b*NP + j)*DIM : nullptr;
  for (int cu = qt*8; cu < qt*8 + 8; cu++) {
    Pack8 pr; pr.u = RAWu[((size_t)(b*32 + cu)*NP + i)*NP + j];
    Pack8 p;
    int cbase = cu*8;
    const float* clp = (WRITE_NEXT && cbase < DIM) ? clrow_i + cbase
                     : (WRITE_NEXT ? clrow_j + (cbase - DIM) : nullptr);
    #pragma unroll
    for (int e = 0; e < 8; e++) {
      int c = cbase + e;
      float v = (float)pr.h[e];
      v = fmaxf(fmaf(v, sscale[c], sshift[c]), 0.f);
      if (WRITE_NEXT) p.h[e] = (__bf16)(v + clp[e]);
      #pragma unroll
      for (int h = 0; h < HH; h++) gacc[h] = fmaf(v, swd[h*C2 + c], gacc[h]);
    }
    if (WRITE_NEXT) {
      size_t unit = ((((size_t)(b*16 + (cu>>1))*PR + (i+1))*PC + (j+8))*2 + (cu&1));
      ((uint4*)inb_next)[unit] = p.u;
    }
  }
  #pragma unroll
  for (int h = 0; h < HH; h++) sg[qt][h][j] = gacc[h];
  __syncthreads();
  if (qt == 0) {
    #pragma unroll
    for (int h = 0; h < HH; h++)
      tg[((size_t)(b*HH + h)*NP + i)*NP + j] = sg[0][h][j] + sg[1][h][j] + sg[2][h][j] + sg[3][h][j];
  }
}

// ---------------- gate = sigmoid(t + t^T + bias), coalesced tiled transpose ----------------
__global__ void k_gate(const float* __restrict__ tg, const float* __restrict__ wdb,
                       float* __restrict__ gate) {
  int tile = blockIdx.x;
  int hb = blockIdx.y;
  int b = hb >> 3, h = hb & 7;
  size_t bh = (size_t)(b*HH + h);
  int ti = tile / 6, tj = tile % 6;
  int r = threadIdx.x >> 3, c4 = threadIdx.x & 7;
  __shared__ float tB[32][33];
  const float* base = tg + bh*NN;
  float4 vb = *(const float4*)(base + (tj*32 + r)*NP + ti*32 + c4*4);
  tB[r][c4*4+0] = vb.x; tB[r][c4*4+1] = vb.y; tB[r][c4*4+2] = vb.z; tB[r][c4*4+3] = vb.w;
  __syncthreads();
  float4 va = *(const float4*)(base + (ti*32 + r)*NP + tj*32 + c4*4);
  float bias = wdb[h];
  float4 o;
  o.x = 1.f / (1.f + expf(-(va.x + tB[c4*4+0][r] + bias)));
  o.y = 1.f / (1.f + expf(-(va.y + tB[c4*4+1][r] + bias)));
  o.z = 1.f / (1.f + expf(-(va.z + tB[c4*4+2][r] + bias)));
  o.w = 1.f / (1.f + expf(-(va.w + tB[c4*4+3][r] + bias)));
  *(float4*)(gate + bh*NN + (ti*32 + r)*NP + tj*32 + c4*4) = o;
}

// ---------------- MEGA-fused attnx: WIDE (384 thr), t-major ccn ----------------
template<int MODE>
__global__ __launch_bounds__(384)
void k_attnx(const float* __restrict__ Q, const float* __restrict__ K,
             const float* __restrict__ V, const float* __restrict__ gate,
             const float* __restrict__ mask,
             float* __restrict__ X,
             const float* __restrict__ wlt, const float* __restrict__ bl,
             const float* __restrict__ ccnT,
             const float* __restrict__ lng, const float* __restrict__ lnb,
             const float* __restrict__ wqt, const float* __restrict__ bq,
             const float* __restrict__ wkt, const float* __restrict__ bk,
             const float* __restrict__ wvt, const float* __restrict__ bv,
             float* __restrict__ Qn, float* __restrict__ Kn, float* __restrict__ Vn,
             const float* __restrict__ fct, const float* __restrict__ fb,
             float* __restrict__ out) {
  int i = blockIdx.x, b = blockIdx.y;
  int tid = threadIdx.x;
  int j = tid % 192, half = tid / 192;
  int lane = tid & 63, wave = tid >> 6;
  __shared__ float sq[DIM];
  __shared__ float sattn[HH][NP];
  __shared__ float spv[3][DIM];
  __shared__ float supd[DIM];
  __shared__ float sy[DIM];
  __shared__ float sxp[3][DIM];
  __shared__ float sredm[HH][3];
  __shared__ float sreds[HH][3];
  __shared__ float sred[2];
  float mk = mask[b*NP + j];

  if (tid < DIM) {
    int h = tid >> 4, d = tid & 15;
    sq[tid] = Q[(((size_t)(b*HH + h))*NP + i)*DHH + d];
  }
  __syncthreads();

  float a[4], gt[4];
  #pragma unroll
  for (int hh = 0; hh < 4; hh++) {
    int h = half*4 + hh;
    size_t bh = (size_t)(b*HH + h);
    const float4* kr = (const float4*)(K + (bh*NP + j)*DHH);
    const float4* qr = (const float4*)(sq + h*DHH);
    float acc = 0.f;
    #pragma unroll
    for (int q4 = 0; q4 < 4; q4++) {
      float4 qv = qr[q4], kv = kr[q4];
      acc = fmaf(qv.x, kv.x, acc); acc = fmaf(qv.y, kv.y, acc);
      acc = fmaf(qv.z, kv.z, acc); acc = fmaf(qv.w, kv.w, acc);
    }
    a[hh] = acc * 0.25f;
    gt[hh] = gate[(bh*NP + i)*NP + j];
  }
  #pragma unroll
  for (int hh = 0; hh < 4; hh++) {
    int h = half*4 + hh;
    float m = a[hh];
    #pragma unroll
    for (int s = 32; s > 0; s >>= 1) m = fmaxf(m, __shfl_xor(m, s));
    if (lane == 0) sredm[h][wave % 3] = m;
  }
  __syncthreads();
  float e[4];
  #pragma unroll
  for (int hh = 0; hh < 4; hh++) {
    int h = half*4 + hh;
    float amax = fmaxf(fmaxf(sredm[h][0], sredm[h][1]), sredm[h][2]);
    e[hh] = expf(a[hh] - amax) * mk;
    float ss = e[hh];
    #pragma unroll
    for (int s = 32; s > 0; s >>= 1) ss += __shfl_xor(ss, s);
    if (lane == 0) sreds[h][wave % 3] = ss;
  }
  __syncthreads();
  #pragma unroll
  for (int hh = 0; hh < 4; hh++) {
    int h = half*4 + hh;
    float denom = sreds[h][0] + sreds[h][1] + sreds[h][2] + 1e-6f;
    sattn[h][j] = (e[hh] / denom) * gt[hh];
  }
  __syncthreads();

  {
    int d = tid & 15, h2 = (tid >> 4) & 7, jseg = tid >> 7;
    size_t bh = (size_t)(b*HH + h2);
    float acc = 0.f;
    for (int jj = jseg*64; jj < jseg*64 + 64; jj++)
      acc = fmaf(sattn[h2][jj], V[(bh*NP + jj)*DHH + d], acc);
    spv[jseg][h2*DHH + d] = acc;
  }
  __syncthreads();
  if (tid < DIM) supd[tid] = spv[0][tid] + spv[1][tid] + spv[2][tid];
  __syncthreads();

  size_t o = (size_t)(b*NP + i)*DIM;
  if (tid < DIM) sy[tid] = X[o + tid] + supd[tid];
  __syncthreads();
  {
    int d2 = tid & 127, ks = tid >> 7;
    int e0 = ks*43, e1 = (ks == 2) ? 128 : e0 + 43;
    float acc = (ks == 0) ? bl[d2] : 0.f;
    for (int ee = e0; ee < e1; ee++) acc = fmaf(wlt[ee*DIM + d2], sy[ee], acc);
    sxp[ks][d2] = acc;
  }
  __syncthreads();
  float xr = 0.f;
  if (tid < DIM) xr = fmaxf(sxp[0][tid] + sxp[1][tid] + sxp[2][tid], 0.f);
  __syncthreads();

  if (MODE == 0) {
    float v = 0.f;
    if (tid < DIM) v = xr + ccnT[o + tid];
    if (tid < DIM) {
      float s = v;
      #pragma unroll
      for (int m = 32; m > 0; m >>= 1) s += __shfl_xor(s, m);
      if (lane == 0) sred[wave] = s;
    }
    __syncthreads();
    float mean = (sred[0] + sred[1]) * (1.f/128.f);
    float dv = v - mean;
    __syncthreads();
    if (tid < DIM) {
      float q = dv*dv;
      #pragma unroll
      for (int m = 32; m > 0; m >>= 1) q += __shfl_xor(q, m);
      if (lane == 0) sred[wave] = q;
    }
    __syncthreads();
    float var = (sred[0] + sred[1]) * (1.f/128.f);
    float rstd = rsqrtf(var + EPS);
    if (tid < DIM) {
      float xn = dv * rstd * lng[tid] + lnb[tid];
      X[o + tid] = xn;
      sy[tid] = xn;
    }
    __syncthreads();
    {
      int d2 = tid & 127, m = tid >> 7;
      const float* wt_m = (m == 0) ? wqt : (m == 1) ? wkt : wvt;
      const float* b_m  = (m == 0) ? bq  : (m == 1) ? bk  : bv;
      float* out_m      = (m == 0) ? Qn  : (m == 1) ? Kn  : Vn;
      float acc = b_m[d2];
      for (int ee = 0; ee < DIM; ee++) acc = fmaf(wt_m[ee*DIM + d2], sy[ee], acc);
      int h = d2 >> 4, dh = d2 & 15;
      out_m[((size_t)(b*HH + h)*NP + i)*DHH + dh] = fmaxf(acc, 0.f);
    }
  } else {
    if (tid < DIM) sy[tid] = xr;
    __syncthreads();
    {
      int d2 = tid & 127, ks = tid >> 7;
      int e0 = ks*43, e1 = (ks == 2) ? 128 : e0 + 43;
      float acc = (ks == 0) ? fb[d2] : 0.f;
      for (int ee = e0; ee < e1; ee++) acc = fmaf(fct[ee*DIM + d2], sy[ee], acc);
      sxp[ks][d2] = acc;
    }
    __syncthreads();
    if (tid < DIM)
      out[o + tid] = fmaxf(sxp[0][tid] + sxp[1][tid] + sxp[2][tid], 0.f);
  }
}

extern "C" void kernel_launch(void* const* d_in, const int* in_sizes, int n_in,
                              void* d_out, int out_size, void* d_ws, size_t ws_size,
                              hipStream_t stream) {
  const float* seq     = (const float*)d_in[0];
  const float* mask    = (const float*)d_in[1];
  const float* conv1_w = (const float*)d_in[2];
  const float* conv2_w = (const float*)d_in[3];
  const float* ln_g    = (const float*)d_in[4];
  const float* ln_b    = (const float*)d_in[5];
  const float* c1d_w   = (const float*)d_in[6];
  const float* bn1_g   = (const float*)d_in[7];
  const float* bn1_b   = (const float*)d_in[8];
  const float* c2d_w   = (const float*)d_in[9];
  const float* bn2_g   = (const float*)d_in[10];
  const float* bn2_b   = (const float*)d_in[11];
  const float* wq_w    = (const float*)d_in[12];
  const float* wq_b    = (const float*)d_in[13];
  const float* wk_w    = (const float*)d_in[14];
  const float* wk_b    = (const float*)d_in[15];
  const float* wv_w    = (const float*)d_in[16];
  const float* wv_b    = (const float*)d_in[17];
  const float* wd_w    = (const float*)d_in[18];
  const float* wd_b    = (const float*)d_in[19];
  const float* wl_w    = (const float*)d_in[20];
  const float* wl_b    = (const float*)d_in[21];
  const float* fc_w    = (const float*)d_in[22];
  const float* fc_b    = (const float*)d_in[23];
  float* out = (float*)d_out;

  float* ws = (float*)d_ws;
  float* X    = ws; ws += BB*NP*DIM;
  float* Cc   = ws; ws += BB*DIM*NP;
  float* CcT  = ws; ws += BB*DIM*NP;
  float* CL0  = ws; ws += BB*DIM*NP;
  float* CL1  = ws; ws += BB*DIM*NP;
  float* CL2  = ws; ws += BB*DIM*NP;
  float* CLT0 = ws; ws += BB*DIM*NP;
  float* CLT1 = ws; ws += BB*DIM*NP;
  float* CLT2 = ws; ws += BB*DIM*NP;
  float* Q0   = ws; ws += BB*NP*DIM;
  float* K0   = ws; ws += BB*NP*DIM;
  float* V0   = ws; ws += BB*NP*DIM;
  float* Q1   = ws; ws += BB*NP*DIM;
  float* K1   = ws; ws += BB*NP*DIM;
  float* V1   = ws; ws += BB*NP*DIM;
  float* TG   = ws; ws += (size_t)BB*HH*NN;
  float* GATE = ws; ws += (size_t)BB*HH*NN;
  float* WQT  = ws; ws += (size_t)LL*DIM*DIM;
  float* WKT  = ws; ws += (size_t)LL*DIM*DIM;
  float* WVT  = ws; ws += (size_t)LL*DIM*DIM;
  float* WLT  = ws; ws += (size_t)LL*DIM*DIM;
  float* FCT  = ws; ws += (size_t)DIM*DIM;
  float* STATALL = ws; ws += 3*2*C2;
  __bf16* RAW = (__bf16*)ws; ws += (size_t)BB*C2*NN/2;
  __bf16* INB = (__bf16*)ws; ws += (size_t)BB*16*PR*PC*2*16/4;
  __bf16* WTB = (__bf16*)ws; ws += (size_t)LL*C2*C2*9/2;

  k_wtrans<<<dim3(16, 13), 256, 0, stream>>>(wq_w, wk_w, wv_w, wl_w, fc_w,
                                             WQT, WKT, WVT, WLT, FCT);
  k_wprep<<<LL*C2, 256, 0, stream>>>(c2d_w, WTB);
  k_conv_init<<<dim3(NP, BB), DIM, 0, stream>>>(seq, conv1_w, conv2_w, X, Cc, CcT);
  k_conv1d_bn_relu<<<DIM, 768, 0, stream>>>(Cc,  c1d_w + 0*(size_t)DIM*DIM*3, bn1_g + 0*DIM, bn1_b + 0*DIM, CL0, CLT0);
  k_conv1d_bn_relu<<<DIM, 768, 0, stream>>>(CL0, c1d_w + 1*(size_t)DIM*DIM*3, bn1_g + 1*DIM, bn1_b + 1*DIM, CL1, CLT1);
  k_conv1d_bn_relu<<<DIM, 768, 0, stream>>>(CL1, c1d_w + 2*(size_t)DIM*DIM*3, bn1_g + 2*DIM, bn1_b + 2*DIM, CL2, CLT2);
  k_make_convin<<<(BB*16*PR*PC*2)/256, 256, 0, stream>>>(CcT, CLT0, INB, STATALL);
  k_lnqkv<<<dim3(NP, BB), 384, 0, stream>>>(X, CLT0, ln_g, ln_b,
                                            WQT, wq_b, WKT, wk_b, WVT, wv_b, Q0, K0, V0);

  // ---- layer 0 ----
  k_conv2d_mfma<<<dim3(3, 24, 16), 256, 0, stream>>>(INB, WTB + 0*(size_t)16*9*2*256*8, RAW, STATALL + 0*2*C2);
  k_bn2_norm_gate<1><<<dim3(NP, BB), 768, 0, stream>>>(RAW, STATALL + 0*2*C2, bn2_g + 0*C2, bn2_b + 0*C2,
                                                       wd_w + 0*(size_t)HH*C2, CLT1, INB, TG);
  k_gate<<<dim3(36, 16), 256, 0, stream>>>(TG, wd_b + 0*HH, GATE);
  k_attnx<0><<<dim3(NP, BB), 384, 0, stream>>>(Q0, K0, V0, GATE, mask, X,
                                               WLT + 0*(size_t)DIM*DIM, wl_b + 0*DIM,
                                               CLT1, ln_g + 1*DIM, ln_b + 1*DIM,
                                               WQT + 1*(size_t)DIM*DIM, wq_b + 1*DIM,
                                               WKT + 1*(size_t)DIM*DIM, wk_b + 1*DIM,
                                               WVT + 1*(size_t)DIM*DIM, wv_b + 1*DIM,
                                               Q1, K1, V1, nullptr, nullptr, nullptr);
  // ---- layer 1 ----
  k_conv2d_mfma<<<dim3(3, 24, 16), 256, 0, stream>>>(INB, WTB + 1*(size_t)16*9*2*256*8, RAW, STATALL + 1*2*C2);
  k_bn2_norm_gate<1><<<dim3(NP, BB), 768, 0, stream>>>(RAW, STATALL + 1*2*C2, bn2_g + 1*C2, bn2_b + 1*C2,
                                                       wd_w + 1*(size_t)HH*C2, CLT2, INB, TG);
  k_gate<<<dim3(36, 16), 256, 0, stream>>>(TG, wd_b + 1*HH, GATE);
  k_attnx<0><<<dim3(NP, BB), 384, 0, stream>>>(Q1, K1, V1, GATE, mask, X,
                                               WLT + 1*(size_t)DIM*DIM, wl_b + 1*DIM,
                                               CLT2, ln_g + 2*DIM, ln_b + 2*DIM,
                                               WQT + 2*(size_t)DIM*DIM, wq_b + 2*DIM,
                                               WKT + 2*(size_t)DIM*DIM, wk_b + 2*DIM,
                                               WVT + 2*(size_t)DIM*DIM, wv_b + 2*DIM,
                                               Q0, K0, V0, nullptr, nullptr, nullptr);
  // ---- layer 2 ----
  k_conv2d_mfma<<<dim3(3, 24, 16), 256, 0, stream>>>(INB, WTB + 2*(size_t)16*9*2*256*8, RAW, STATALL + 2*2*C2);
  k_bn2_norm_gate<0><<<dim3(NP, BB), 768, 0, stream>>>(RAW, STATALL + 2*2*C2, bn2_g + 2*C2, bn2_b + 2*C2,
                                                       wd_w + 2*(size_t)HH*C2, nullptr, nullptr, TG);
  k_gate<<<dim3(36, 16), 256, 0, stream>>>(TG, wd_b + 2*HH, GATE);
  k_attnx<1><<<dim3(NP, BB), 384, 0, stream>>>(Q0, K0, V0, GATE, mask, X,
                                               WLT + 2*(size_t)DIM*DIM, wl_b + 2*DIM,
                                               nullptr, nullptr, nullptr,
                                               nullptr, nullptr, nullptr, nullptr, nullptr, nullptr,
                                               nullptr, nullptr, nullptr,
                                               FCT, fc_b, out);
}